// Round 4
// baseline (4413.295 us; speedup 1.0000x reference)
//
#include <hip/hip_runtime.h>
#include <hip/hip_bf16.h>

// Transformer-XL RelPartialLearnableMultiHeadAttn — round 4 (resubmit; rounds 1-3
// all died on an unresponsive container before the source was delivered).
// Pipeline: proj_qkv (GEMM) -> proj_r (GEMM) -> fused flash attention w/ rel-shift,
// mask, online softmax, entropy -> entropy reduce -> out projection (GEMM).

#define QLEN 1024
#define MLEN 1024
#define KLEN 2048   // QLEN + MLEN
#define BSZ 8
#define DMODEL 512
#define NHEAD 8
#define DHEAD 64
#define SCALE 0.125f  // 1/sqrt(64)

// workspace layout (float offsets)
#define WS_Q   0                                        // [b][n][i=0..1023][d]   4,194,304
#define WS_K   (WS_Q  + BSZ*NHEAD*QLEN*DHEAD)           // [b][n][j=0..2047][d]   8,388,608
#define WS_V   (WS_K  + BSZ*NHEAD*KLEN*DHEAD)           // [b][n][j][d]           8,388,608
#define WS_R   (WS_V  + BSZ*NHEAD*KLEN*DHEAD)           // [n][rd=0..2047][d]     1,048,576
#define WS_AV  (WS_R  + NHEAD*KLEN*DHEAD)               // [i*8+b][n*64+d]        4,194,304
#define WS_ENT (WS_AV + QLEN*BSZ*DMODEL)                // [bn][iblk] partials    256

// ---------------------------------------------------------------------------
// Tiled fp32 GEMM, 64x64 tile, BK=32, 256 threads, 4x4 per thread. K fixed 512.
// MODE 0: A = cat(mems,w) gather, B = W_qkv (ldb 1536), C scatter -> Q/K/V in ws
// MODE 1: A = r,  B = W_r (ldb 512),  C -> R [n][m][d]
// MODE 2: A = attn_vec, B = W_o (ldb 512), C -> d_out row-major
// ---------------------------------------------------------------------------
template<int MODE>
__global__ __launch_bounds__(256) void gemm64(const float* __restrict__ A,
                                              const float* __restrict__ A2,
                                              const float* __restrict__ B,
                                              float* __restrict__ C) {
    constexpr int LDB = (MODE == 0) ? 1536 : 512;
    __shared__ float As[64][36];
    __shared__ float Bs[32][68];
    const int tid = threadIdx.x;
    const int tx = tid & 15, ty = tid >> 4;
    const int n0 = blockIdx.x * 64;
    const int m0 = blockIdx.y * 64;

    float acc[4][4] = {};

    for (int k0 = 0; k0 < 512; k0 += 32) {
        // stage A tile: 64 rows x 32 cols
        #pragma unroll
        for (int r2 = 0; r2 < 2; ++r2) {
            int row = (tid >> 3) + r2 * 32;
            int c4  = (tid & 7) * 4;
            int m = m0 + row;
            const float* src;
            if (MODE == 0) {
                int t = m >> 3, b = m & 7;
                src = (t < MLEN) ? (A  + ((size_t)t * BSZ + b) * DMODEL)
                                 : (A2 + ((size_t)(t - MLEN) * BSZ + b) * DMODEL);
            } else {
                src = A + (size_t)m * 512;
            }
            *reinterpret_cast<float4*>(&As[row][c4]) =
                *reinterpret_cast<const float4*>(src + k0 + c4);
        }
        // stage B tile: 32 k x 64 cols
        #pragma unroll
        for (int r2 = 0; r2 < 2; ++r2) {
            int kk = (tid >> 4) + r2 * 16;
            int c4 = (tid & 15) * 4;
            *reinterpret_cast<float4*>(&Bs[kk][c4]) =
                *reinterpret_cast<const float4*>(B + (size_t)(k0 + kk) * LDB + n0 + c4);
        }
        __syncthreads();
        #pragma unroll
        for (int k = 0; k < 32; ++k) {
            float a0 = As[ty*4+0][k], a1 = As[ty*4+1][k];
            float a2 = As[ty*4+2][k], a3 = As[ty*4+3][k];
            float4 bv = *reinterpret_cast<const float4*>(&Bs[k][tx*4]);
            acc[0][0] += a0*bv.x; acc[0][1] += a0*bv.y; acc[0][2] += a0*bv.z; acc[0][3] += a0*bv.w;
            acc[1][0] += a1*bv.x; acc[1][1] += a1*bv.y; acc[1][2] += a1*bv.z; acc[1][3] += a1*bv.w;
            acc[2][0] += a2*bv.x; acc[2][1] += a2*bv.y; acc[2][2] += a2*bv.z; acc[2][3] += a2*bv.w;
            acc[3][0] += a3*bv.x; acc[3][1] += a3*bv.y; acc[3][2] += a3*bv.z; acc[3][3] += a3*bv.w;
        }
        __syncthreads();
    }

    const int c = n0 + tx * 4;
    #pragma unroll
    for (int ii = 0; ii < 4; ++ii) {
        int m = m0 + ty * 4 + ii;
        float4 v = make_float4(acc[ii][0], acc[ii][1], acc[ii][2], acc[ii][3]);
        if (MODE == 2) {
            *reinterpret_cast<float4*>(C + (size_t)m * 512 + c) = v;
        } else if (MODE == 1) {
            int n = c >> 6, d = c & 63;
            *reinterpret_cast<float4*>(C + ((size_t)n * KLEN + m) * DHEAD + d) = v;
        } else {
            int t = m >> 3, b = m & 7;
            int region = c >> 9, cr = c & 511;
            int n = cr >> 6, d = cr & 63;
            float* dst;
            if (region == 0) {
                if (t < MLEN) continue;      // only last QLEN rows produce Q
                dst = C + WS_Q + (((size_t)(b * NHEAD + n) * QLEN + (t - MLEN)) << 6) + d;
            } else if (region == 1) {
                dst = C + WS_K + (((size_t)(b * NHEAD + n) * KLEN + t) << 6) + d;
            } else {
                dst = C + WS_V + (((size_t)(b * NHEAD + n) * KLEN + t) << 6) + d;
            }
            *reinterpret_cast<float4*>(dst) = v;
        }
    }
}

// ---------------------------------------------------------------------------
// Fused attention: grid (4 i-blocks, 64 bn), 256 threads, one thread per q-row.
// Per j-tile (32 rows) K/V staged in LDS; BD term reads R rows from global
// (rd = j + QLEN-1 - i), L1/L2 cached. Online softmax + entropy accumulators.
// ---------------------------------------------------------------------------
__global__ __launch_bounds__(256) void attn_kernel(float* __restrict__ ws,
                                                   const float* __restrict__ rwb,
                                                   const float* __restrict__ rrb) {
    __shared__ float Ks[32][68];
    __shared__ float Vs[32][68];
    __shared__ float wbS[64], dfS[64];
    __shared__ float redS[256];

    const int tid  = threadIdx.x;
    const int iblk = blockIdx.x;       // 0..3
    const int bn   = blockIdx.y;       // b*8 + n
    const int b    = bn >> 3, n = bn & 7;

    const float* Qb = ws + WS_Q + ((size_t)bn * QLEN) * DHEAD;
    const float* Kb = ws + WS_K + ((size_t)bn * KLEN) * DHEAD;
    const float* Vb = ws + WS_V + ((size_t)bn * KLEN) * DHEAD;
    const float* Rn = ws + WS_R + ((size_t)n * KLEN) * DHEAD;

    if (tid < 64) {
        float wb = rwb[n * 64 + tid];
        wbS[tid] = wb;
        dfS[tid] = rrb[n * 64 + tid] - wb;   // qr = qw + (rrb - rwb)
    }
    __syncthreads();

    const int i = iblk * 256 + tid;
    float qw[64];
    #pragma unroll
    for (int d4 = 0; d4 < 64; d4 += 4) {
        float4 v = *reinterpret_cast<const float4*>(Qb + ((size_t)i << 6) + d4);
        qw[d4+0] = v.x + wbS[d4+0];
        qw[d4+1] = v.y + wbS[d4+1];
        qw[d4+2] = v.z + wbS[d4+2];
        qw[d4+3] = v.w + wbS[d4+3];
    }

    float O[64];
    #pragma unroll
    for (int d = 0; d < 64; ++d) O[d] = 0.f;
    float mrun = -1e30f, lsum = 0.f, tsum = 0.f;

    const int jmax_t   = i + MLEN;                                 // last valid j
    const int jmax_blk = min(KLEN - 1, iblk * 256 + 255 + MLEN);

    for (int j0 = 0; j0 <= jmax_blk; j0 += 32) {
        __syncthreads();
        #pragma unroll
        for (int r = 0; r < 2; ++r) {
            int idx = tid + r * 256;
            int row = idx >> 4, c4 = (idx & 15) * 4;
            *reinterpret_cast<float4*>(&Ks[row][c4]) =
                *reinterpret_cast<const float4*>(Kb + (size_t)(j0 + row) * DHEAD + c4);
            *reinterpret_cast<float4*>(&Vs[row][c4]) =
                *reinterpret_cast<const float4*>(Vb + (size_t)(j0 + row) * DHEAD + c4);
        }
        __syncthreads();

        const int jjend = min(32, jmax_t - j0 + 1);
        const float* Rrow = Rn + (size_t)(j0 + (QLEN - 1) - i) * DHEAD;
        for (int jj = 0; jj < jjend; ++jj, Rrow += DHEAD) {
            float sac = 0.f, sbd = 0.f;
            #pragma unroll
            for (int d4 = 0; d4 < 64; d4 += 4) {
                float4 kv = *reinterpret_cast<const float4*>(&Ks[jj][d4]);
                float4 rv = *reinterpret_cast<const float4*>(Rrow + d4);
                sac += qw[d4+0]*kv.x + qw[d4+1]*kv.y + qw[d4+2]*kv.z + qw[d4+3]*kv.w;
                sbd += (qw[d4+0]+dfS[d4+0])*rv.x + (qw[d4+1]+dfS[d4+1])*rv.y
                     + (qw[d4+2]+dfS[d4+2])*rv.z + (qw[d4+3]+dfS[d4+3])*rv.w;
            }
            float s = (sac + sbd) * SCALE;
            if (s > mrun) {
                float csc = __expf(mrun - s);
                mrun = s;
                lsum *= csc; tsum *= csc;
                #pragma unroll
                for (int d = 0; d < 64; ++d) O[d] *= csc;
            }
            float e = __expf(s - mrun);
            lsum += e;
            tsum += e * s;
            #pragma unroll
            for (int d4 = 0; d4 < 64; d4 += 4) {
                float4 vv = *reinterpret_cast<const float4*>(&Vs[jj][d4]);
                O[d4+0] += e * vv.x; O[d4+1] += e * vv.y;
                O[d4+2] += e * vv.z; O[d4+3] += e * vv.w;
            }
        }
    }

    const float inv = 1.f / lsum;
    float* outp = ws + WS_AV + ((size_t)i * BSZ + b) * DMODEL + n * 64;
    #pragma unroll
    for (int d4 = 0; d4 < 64; d4 += 4) {
        float4 v = make_float4(O[d4]*inv, O[d4+1]*inv, O[d4+2]*inv, O[d4+3]*inv);
        *reinterpret_cast<float4*>(outp + d4) = v;
    }

    // entropy: H = m + log(l) - t/l ; block-sum -> partial
    float H = mrun + __logf(lsum) - tsum * inv;
    redS[tid] = H;
    __syncthreads();
    for (int sdist = 128; sdist > 0; sdist >>= 1) {
        if (tid < sdist) redS[tid] += redS[tid + sdist];
        __syncthreads();
    }
    if (tid == 0) ws[WS_ENT + (size_t)bn * 4 + iblk] = redS[0];
}

__global__ void reduce_ent(const float* __restrict__ ws, float* __restrict__ out) {
    int n = threadIdx.x;
    if (n < NHEAD) {
        float s = 0.f;
        for (int b = 0; b < BSZ; ++b)
            for (int ib = 0; ib < 4; ++ib)
                s += ws[WS_ENT + (b * NHEAD + n) * 4 + ib];
        out[(size_t)QLEN * BSZ * DMODEL + n] = s / (float)(QLEN * BSZ);
    }
}

extern "C" void kernel_launch(void* const* d_in, const int* in_sizes, int n_in,
                              void* d_out, int out_size, void* d_ws, size_t ws_size,
                              hipStream_t stream) {
    const float* w    = (const float*)d_in[0];
    const float* r    = (const float*)d_in[1];
    const float* rwb  = (const float*)d_in[2];
    const float* rrb  = (const float*)d_in[3];
    const float* mems = (const float*)d_in[4];
    // d_in[5] = attn_mask: deterministic (j > i + MLEN), recomputed on device
    const float* Wqkv = (const float*)d_in[6];
    const float* Wr   = (const float*)d_in[7];
    const float* Wo   = (const float*)d_in[8];
    float* out = (float*)d_out;
    float* ws  = (float*)d_ws;

    // QKV projection: (16384 x 512) @ (512 x 1536) -> scatter Q/K/V
    gemm64<0><<<dim3(24, 256), 256, 0, stream>>>(mems, w, Wqkv, ws);
    // R projection: (2048 x 512) @ (512 x 512) -> R[n][rd][d]
    gemm64<1><<<dim3(8, 32), 256, 0, stream>>>(r, nullptr, Wr, ws + WS_R);
    // fused attention
    attn_kernel<<<dim3(4, 64), 256, 0, stream>>>(ws, rwb, rrb);
    // entropy reduction -> out[4194304 .. 4194312)
    reduce_ent<<<1, 64, 0, stream>>>(ws, out);
    // output projection: (8192 x 512) @ (512 x 512) -> attn_out
    gemm64<2><<<dim3(8, 128), 256, 0, stream>>>(ws + WS_AV, nullptr, Wo, out);
}

// Round 5
// 654.823 us; speedup vs baseline: 6.7397x; 6.7397x over previous
//
#include <hip/hip_runtime.h>
#include <hip/hip_bf16.h>

// Transformer-XL RelPartialLearnableMultiHeadAttn — round 5: MFMA attention.
// proj_qkv (fp32 GEMM -> bf16 QW/QR/K/Vt) ; proj_r -> bf16 R (padded) ;
// attn: per 64-row i-tile x bn block, mfma 16x16x32_bf16 for AC, banded BD
// (G16 + diagonal gather), register online softmax + entropy, PV via P-LDS.

#define QLEN 1024
#define MLEN 1024
#define KLEN 2048
#define BSZ 8
#define DMODEL 512
#define NHEAD 8
#define DHEAD 64
#define SCALE 0.125f
#define RPAD 2176   // R rows incl. zero pad (band reads up to 2111)

// workspace byte offsets
#define B_QW  0u                       // bf16 [bn][1024][64]
#define B_QR  (B_QW + 8388608u)        // bf16 [bn][1024][64]
#define B_K   (B_QR + 8388608u)        // bf16 [bn][2048][64]
#define B_VT  (B_K  + 16777216u)       // bf16 [bn][64][2048]
#define B_R   (B_VT + 16777216u)       // bf16 [n][2176][64]
#define B_AV  (B_R  + 2228224u)        // f32  [i*8+b][512]
#define B_ENT (B_AV + 16777216u)       // f32  [bn][16]

typedef short bf16x8 __attribute__((ext_vector_type(8)));
typedef float f32x4  __attribute__((ext_vector_type(4)));

__device__ __forceinline__ unsigned short f2bf(float f) {
    union { float f; unsigned int u; } v; v.f = f;
    unsigned int r = v.u + 0x7FFFu + ((v.u >> 16) & 1u);
    return (unsigned short)(r >> 16);
}

// ---------------------------------------------------------------------------
// QKV projection: (16384 x 512) @ (512 x 1536) fp32 core, bf16 scatter epilogue.
// ---------------------------------------------------------------------------
__global__ __launch_bounds__(256) void gemm_qkv(const float* __restrict__ mems,
                                                const float* __restrict__ w,
                                                const float* __restrict__ B,
                                                const float* __restrict__ rwb,
                                                const float* __restrict__ rrb,
                                                unsigned short* __restrict__ QW,
                                                unsigned short* __restrict__ QR,
                                                unsigned short* __restrict__ Kg,
                                                unsigned short* __restrict__ VT) {
    __shared__ float As[64][36];
    __shared__ float Bs[32][68];
    const int tid = threadIdx.x;
    const int tx = tid & 15, ty = tid >> 4;
    const int n0 = blockIdx.x * 64;
    const int m0 = blockIdx.y * 64;

    float acc[4][4] = {};
    for (int k0 = 0; k0 < 512; k0 += 32) {
        #pragma unroll
        for (int r2 = 0; r2 < 2; ++r2) {
            int row = (tid >> 3) + r2 * 32;
            int c4  = (tid & 7) * 4;
            int m = m0 + row;
            int t = m >> 3, b = m & 7;
            const float* src = (t < MLEN) ? (mems + ((size_t)t * BSZ + b) * DMODEL)
                                          : (w    + ((size_t)(t - MLEN) * BSZ + b) * DMODEL);
            *reinterpret_cast<float4*>(&As[row][c4]) =
                *reinterpret_cast<const float4*>(src + k0 + c4);
        }
        #pragma unroll
        for (int r2 = 0; r2 < 2; ++r2) {
            int kk = (tid >> 4) + r2 * 16;
            int c4 = (tid & 15) * 4;
            *reinterpret_cast<float4*>(&Bs[kk][c4]) =
                *reinterpret_cast<const float4*>(B + (size_t)(k0 + kk) * 1536 + n0 + c4);
        }
        __syncthreads();
        #pragma unroll
        for (int k = 0; k < 32; ++k) {
            float a0 = As[ty*4+0][k], a1 = As[ty*4+1][k];
            float a2 = As[ty*4+2][k], a3 = As[ty*4+3][k];
            float4 bv = *reinterpret_cast<const float4*>(&Bs[k][tx*4]);
            acc[0][0] += a0*bv.x; acc[0][1] += a0*bv.y; acc[0][2] += a0*bv.z; acc[0][3] += a0*bv.w;
            acc[1][0] += a1*bv.x; acc[1][1] += a1*bv.y; acc[1][2] += a1*bv.z; acc[1][3] += a1*bv.w;
            acc[2][0] += a2*bv.x; acc[2][1] += a2*bv.y; acc[2][2] += a2*bv.z; acc[2][3] += a2*bv.w;
            acc[3][0] += a3*bv.x; acc[3][1] += a3*bv.y; acc[3][2] += a3*bv.z; acc[3][3] += a3*bv.w;
        }
        __syncthreads();
    }

    const int c = n0 + tx * 4;
    const int region = c >> 9, cr = c & 511;
    const int n = cr >> 6, d = cr & 63;
    float b0 = 0, b1 = 0, b2 = 0, b3 = 0, c0 = 0, c1 = 0, c2 = 0, c3 = 0;
    if (region == 0) {
        b0 = rwb[n*64+d+0]; b1 = rwb[n*64+d+1]; b2 = rwb[n*64+d+2]; b3 = rwb[n*64+d+3];
        c0 = rrb[n*64+d+0]; c1 = rrb[n*64+d+1]; c2 = rrb[n*64+d+2]; c3 = rrb[n*64+d+3];
    }
    #pragma unroll
    for (int ii = 0; ii < 4; ++ii) {
        int m = m0 + ty * 4 + ii;
        int t = m >> 3, b = m & 7;
        int bn = b * NHEAD + n;
        if (region == 0) {
            if (t < MLEN) continue;
            size_t base = ((size_t)bn * QLEN + (t - MLEN)) * 64 + d;
            ushort4 vw, vr;
            vw.x = f2bf(acc[ii][0] + b0); vw.y = f2bf(acc[ii][1] + b1);
            vw.z = f2bf(acc[ii][2] + b2); vw.w = f2bf(acc[ii][3] + b3);
            vr.x = f2bf(acc[ii][0] + c0); vr.y = f2bf(acc[ii][1] + c1);
            vr.z = f2bf(acc[ii][2] + c2); vr.w = f2bf(acc[ii][3] + c3);
            *reinterpret_cast<ushort4*>(QW + base) = vw;
            *reinterpret_cast<ushort4*>(QR + base) = vr;
        } else if (region == 1) {
            size_t base = ((size_t)bn * KLEN + t) * 64 + d;
            ushort4 v;
            v.x = f2bf(acc[ii][0]); v.y = f2bf(acc[ii][1]);
            v.z = f2bf(acc[ii][2]); v.w = f2bf(acc[ii][3]);
            *reinterpret_cast<ushort4*>(Kg + base) = v;
        } else {
            #pragma unroll
            for (int e = 0; e < 4; ++e)
                VT[((size_t)bn * 64 + d + e) * KLEN + t] = f2bf(acc[ii][e]);
        }
    }
}

// ---------------------------------------------------------------------------
// R projection: (2048 x 512) @ (512 x 512) -> bf16 R [n][2176][64]
// ---------------------------------------------------------------------------
__global__ __launch_bounds__(256) void gemm_r(const float* __restrict__ A,
                                              const float* __restrict__ B,
                                              unsigned short* __restrict__ Rg) {
    __shared__ float As[64][36];
    __shared__ float Bs[32][68];
    const int tid = threadIdx.x;
    const int tx = tid & 15, ty = tid >> 4;
    const int n0 = blockIdx.x * 64;
    const int m0 = blockIdx.y * 64;

    float acc[4][4] = {};
    for (int k0 = 0; k0 < 512; k0 += 32) {
        #pragma unroll
        for (int r2 = 0; r2 < 2; ++r2) {
            int row = (tid >> 3) + r2 * 32;
            int c4  = (tid & 7) * 4;
            *reinterpret_cast<float4*>(&As[row][c4]) =
                *reinterpret_cast<const float4*>(A + (size_t)(m0 + row) * 512 + k0 + c4);
        }
        #pragma unroll
        for (int r2 = 0; r2 < 2; ++r2) {
            int kk = (tid >> 4) + r2 * 16;
            int c4 = (tid & 15) * 4;
            *reinterpret_cast<float4*>(&Bs[kk][c4]) =
                *reinterpret_cast<const float4*>(B + (size_t)(k0 + kk) * 512 + n0 + c4);
        }
        __syncthreads();
        #pragma unroll
        for (int k = 0; k < 32; ++k) {
            float a0 = As[ty*4+0][k], a1 = As[ty*4+1][k];
            float a2 = As[ty*4+2][k], a3 = As[ty*4+3][k];
            float4 bv = *reinterpret_cast<const float4*>(&Bs[k][tx*4]);
            acc[0][0] += a0*bv.x; acc[0][1] += a0*bv.y; acc[0][2] += a0*bv.z; acc[0][3] += a0*bv.w;
            acc[1][0] += a1*bv.x; acc[1][1] += a1*bv.y; acc[1][2] += a1*bv.z; acc[1][3] += a1*bv.w;
            acc[2][0] += a2*bv.x; acc[2][1] += a2*bv.y; acc[2][2] += a2*bv.z; acc[2][3] += a2*bv.w;
            acc[3][0] += a3*bv.x; acc[3][1] += a3*bv.y; acc[3][2] += a3*bv.z; acc[3][3] += a3*bv.w;
        }
        __syncthreads();
    }
    const int c = n0 + tx * 4;
    const int n = c >> 6, d = c & 63;
    #pragma unroll
    for (int ii = 0; ii < 4; ++ii) {
        int m = m0 + ty * 4 + ii;
        ushort4 v;
        v.x = f2bf(acc[ii][0]); v.y = f2bf(acc[ii][1]);
        v.z = f2bf(acc[ii][2]); v.w = f2bf(acc[ii][3]);
        *reinterpret_cast<ushort4*>(Rg + ((size_t)n * RPAD + m) * 64 + d) = v;
    }
}

__global__ void zpad_r(unsigned short* __restrict__ Rg) {
    int idx = blockIdx.x * 256 + threadIdx.x;   // 0..8191
    int n = idx >> 10, o = idx & 1023;
    uint4 z = make_uint4(0, 0, 0, 0);
    *reinterpret_cast<uint4*>(Rg + ((size_t)n * RPAD + KLEN) * 64 + o * 8) = z;
}

// ---------------------------------------------------------------------------
// MFMA attention. grid (16 i-tiles, 64 bn), 256 threads = 4 waves.
// Wave w owns output rows 16w..16w+15 of the 64-row tile.
// ---------------------------------------------------------------------------
__global__ __launch_bounds__(256) void attn_mfma(const unsigned short* __restrict__ QWg,
                                                 const unsigned short* __restrict__ QRg,
                                                 const unsigned short* __restrict__ Kg,
                                                 const unsigned short* __restrict__ VTg,
                                                 const unsigned short* __restrict__ Rg,
                                                 float* __restrict__ AV,
                                                 float* __restrict__ ENT) {
    __shared__ unsigned short Klds[64][72];
    __shared__ unsigned short Rblds[128][72];
    __shared__ unsigned short Vtlds[64][72];
    __shared__ unsigned short Plds[64][72];
    __shared__ float Gscr[4][16][36];
    __shared__ float hred[4];

    const int tid = threadIdx.x;
    const int w = tid >> 6, lane = tid & 63, lg = lane >> 4, lc = lane & 15;
    const int i0 = blockIdx.x * 64;
    const int bn = blockIdx.y, b = bn >> 3, n = bn & 7;

    // stage QW/QR tiles (reuse Klds/Rblds), then pull persistent A-frags
    {
        const unsigned short* qwsrc = QWg + ((size_t)bn * QLEN + i0) * 64;
        const unsigned short* qrsrc = QRg + ((size_t)bn * QLEN + i0) * 64;
        #pragma unroll
        for (int q = 0; q < 2; ++q) {
            int idx = tid * 2 + q;
            int row = idx >> 3, c8 = (idx & 7) * 8;
            *reinterpret_cast<uint4*>(&Klds[row][c8])  = *reinterpret_cast<const uint4*>(qwsrc + row * 64 + c8);
            *reinterpret_cast<uint4*>(&Rblds[row][c8]) = *reinterpret_cast<const uint4*>(qrsrc + row * 64 + c8);
        }
    }
    __syncthreads();
    bf16x8 aqw[2], aqr[2];
    #pragma unroll
    for (int k = 0; k < 2; ++k) {
        aqw[k] = *reinterpret_cast<const bf16x8*>(&Klds[16 * w + lc][32 * k + lg * 8]);
        aqr[k] = *reinterpret_cast<const bf16x8*>(&Rblds[16 * w + lc][32 * k + lg * 8]);
    }

    f32x4 Ofr[4];
    #pragma unroll
    for (int t = 0; t < 4; ++t) Ofr[t] = (f32x4){0.f, 0.f, 0.f, 0.f};
    float mreg[4] = {-1e30f, -1e30f, -1e30f, -1e30f};
    float lreg[4] = {0.f, 0.f, 0.f, 0.f};
    float treg[4] = {0.f, 0.f, 0.f, 0.f};

    const int nj = (i0 >> 6) + 17;
    const unsigned short* kbase = Kg  + (size_t)bn * KLEN * 64;
    const unsigned short* vbase = VTg + (size_t)bn * 64 * KLEN;
    const unsigned short* rbase = Rg  + (size_t)n * RPAD * 64 + (size_t)(960 - i0) * 64;

    for (int jt = 0; jt < nj; ++jt) {
        const int j0 = jt * 64;
        __syncthreads();
        #pragma unroll
        for (int q = 0; q < 2; ++q) {
            int idx = tid * 2 + q, row = idx >> 3, c8 = (idx & 7) * 8;
            *reinterpret_cast<uint4*>(&Klds[row][c8]) =
                *reinterpret_cast<const uint4*>(kbase + (size_t)(j0 + row) * 64 + c8);
            *reinterpret_cast<uint4*>(&Vtlds[row][c8]) =
                *reinterpret_cast<const uint4*>(vbase + (size_t)row * KLEN + j0 + c8);
        }
        #pragma unroll
        for (int q = 0; q < 4; ++q) {
            int idx = tid * 4 + q, row = idx >> 3, c8 = (idx & 7) * 8;
            *reinterpret_cast<uint4*>(&Rblds[row][c8]) =
                *reinterpret_cast<const uint4*>(rbase + (size_t)(j0 + row) * 64 + c8);
        }
        __syncthreads();

        // ---- scores: AC (MFMA) + banded BD (MFMA + gather), mask, scale ----
        f32x4 sfr[4];
        #pragma unroll
        for (int bj = 0; bj < 4; ++bj) {
            f32x4 acc = (f32x4){0.f, 0.f, 0.f, 0.f};
            #pragma unroll
            for (int k = 0; k < 2; ++k) {
                bf16x8 bk = *reinterpret_cast<const bf16x8*>(&Klds[16 * bj + lc][32 * k + lg * 8]);
                acc = __builtin_amdgcn_mfma_f32_16x16x32_bf16(aqw[k], bk, acc, 0, 0, 0);
            }
            f32x4 g0 = (f32x4){0.f, 0.f, 0.f, 0.f}, g1 = (f32x4){0.f, 0.f, 0.f, 0.f};
            const int obase = 16 * (bj - w) + 48;
            #pragma unroll
            for (int k = 0; k < 2; ++k) {
                bf16x8 br0 = *reinterpret_cast<const bf16x8*>(&Rblds[obase + lc][32 * k + lg * 8]);
                bf16x8 br1 = *reinterpret_cast<const bf16x8*>(&Rblds[obase + 16 + lc][32 * k + lg * 8]);
                g0 = __builtin_amdgcn_mfma_f32_16x16x32_bf16(aqr[k], br0, g0, 0, 0, 0);
                g1 = __builtin_amdgcn_mfma_f32_16x16x32_bf16(aqr[k], br1, g1, 0, 0, 0);
            }
            #pragma unroll
            for (int reg = 0; reg < 4; ++reg) {
                Gscr[w][lg * 4 + reg][lc]      = g0[reg];
                Gscr[w][lg * 4 + reg][16 + lc] = g1[reg];
            }
            asm volatile("s_waitcnt lgkmcnt(0)" ::: "memory");
            __builtin_amdgcn_sched_barrier(0);
            #pragma unroll
            for (int reg = 0; reg < 4; ++reg) {
                int r = lg * 4 + reg;
                int ii = 16 * w + r;
                int jj = 16 * bj + lc;
                float g = Gscr[w][r][lc - r + 15];
                float s = (acc[reg] + g) * SCALE;
                bool valid = (j0 + jj) <= (i0 + ii + MLEN);
                sfr[bj][reg] = valid ? s : -1e30f;
            }
        }

        // ---- register online softmax + entropy accumulators ----
        float pf[4][4];
        #pragma unroll
        for (int reg = 0; reg < 4; ++reg) {
            float gmax = fmaxf(fmaxf(sfr[0][reg], sfr[1][reg]), fmaxf(sfr[2][reg], sfr[3][reg]));
            gmax = fmaxf(gmax, __shfl_xor(gmax, 1));
            gmax = fmaxf(gmax, __shfl_xor(gmax, 2));
            gmax = fmaxf(gmax, __shfl_xor(gmax, 4));
            gmax = fmaxf(gmax, __shfl_xor(gmax, 8));
            float mo = mreg[reg];
            float mn = fmaxf(mo, gmax);
            float le = 0.f, te = 0.f;
            #pragma unroll
            for (int bj = 0; bj < 4; ++bj) {
                float e = __expf(sfr[bj][reg] - mn);
                le += e; te += e * sfr[bj][reg];
                pf[bj][reg] = e;
            }
            le += __shfl_xor(le, 1); le += __shfl_xor(le, 2);
            le += __shfl_xor(le, 4); le += __shfl_xor(le, 8);
            te += __shfl_xor(te, 1); te += __shfl_xor(te, 2);
            te += __shfl_xor(te, 4); te += __shfl_xor(te, 8);
            float fac = __expf(mo - mn);
            lreg[reg] = lreg[reg] * fac + le;
            treg[reg] = treg[reg] * fac + te;
            mreg[reg] = mn;
            Ofr[0][reg] *= fac; Ofr[1][reg] *= fac;
            Ofr[2][reg] *= fac; Ofr[3][reg] *= fac;
            int r = lg * 4 + reg;
            #pragma unroll
            for (int bj = 0; bj < 4; ++bj)
                Plds[16 * w + r][16 * bj + lc] = f2bf(pf[bj][reg]);
        }
        asm volatile("s_waitcnt lgkmcnt(0)" ::: "memory");
        __builtin_amdgcn_sched_barrier(0);

        // ---- PV ----
        #pragma unroll
        for (int k = 0; k < 2; ++k) {
            bf16x8 ap = *reinterpret_cast<const bf16x8*>(&Plds[16 * w + lc][32 * k + lg * 8]);
            Ofr[0] = __builtin_amdgcn_mfma_f32_16x16x32_bf16(ap,
                *reinterpret_cast<const bf16x8*>(&Vtlds[ 0 + lc][32 * k + lg * 8]), Ofr[0], 0, 0, 0);
            Ofr[1] = __builtin_amdgcn_mfma_f32_16x16x32_bf16(ap,
                *reinterpret_cast<const bf16x8*>(&Vtlds[16 + lc][32 * k + lg * 8]), Ofr[1], 0, 0, 0);
            Ofr[2] = __builtin_amdgcn_mfma_f32_16x16x32_bf16(ap,
                *reinterpret_cast<const bf16x8*>(&Vtlds[32 + lc][32 * k + lg * 8]), Ofr[2], 0, 0, 0);
            Ofr[3] = __builtin_amdgcn_mfma_f32_16x16x32_bf16(ap,
                *reinterpret_cast<const bf16x8*>(&Vtlds[48 + lc][32 * k + lg * 8]), Ofr[3], 0, 0, 0);
        }
    }

    // ---- normalize + write attn_vec (fp32) ----
    #pragma unroll
    for (int reg = 0; reg < 4; ++reg) {
        int i = i0 + 16 * w + lg * 4 + reg;
        float inv = 1.f / lreg[reg];
        float* dst = AV + ((size_t)i * BSZ + b) * DMODEL + n * 64 + lc;
        dst[ 0] = Ofr[0][reg] * inv;
        dst[16] = Ofr[1][reg] * inv;
        dst[32] = Ofr[2][reg] * inv;
        dst[48] = Ofr[3][reg] * inv;
    }

    // ---- entropy partial: one contribution per row (lc==0 lanes) ----
    float h = 0.f;
    if (lc == 0) {
        #pragma unroll
        for (int reg = 0; reg < 4; ++reg)
            h += mreg[reg] + __logf(lreg[reg]) - treg[reg] / lreg[reg];
    }
    h += __shfl_xor(h, 1);  h += __shfl_xor(h, 2);  h += __shfl_xor(h, 4);
    h += __shfl_xor(h, 8);  h += __shfl_xor(h, 16); h += __shfl_xor(h, 32);
    if (lane == 0) hred[w] = h;
    __syncthreads();
    if (tid == 0) ENT[bn * 16 + (i0 >> 6)] = hred[0] + hred[1] + hred[2] + hred[3];
}

__global__ void reduce_ent(const float* __restrict__ ent, float* __restrict__ out) {
    int n = threadIdx.x;
    if (n < NHEAD) {
        float s = 0.f;
        for (int b = 0; b < BSZ; ++b)
            for (int it = 0; it < 16; ++it)
                s += ent[(b * NHEAD + n) * 16 + it];
        out[(size_t)QLEN * BSZ * DMODEL + n] = s / (float)(QLEN * BSZ);
    }
}

// ---------------------------------------------------------------------------
// Output projection: (8192 x 512) @ (512 x 512) fp32 -> d_out
// ---------------------------------------------------------------------------
__global__ __launch_bounds__(256) void gemm_out(const float* __restrict__ A,
                                                const float* __restrict__ B,
                                                float* __restrict__ C) {
    __shared__ float As[64][36];
    __shared__ float Bs[32][68];
    const int tid = threadIdx.x;
    const int tx = tid & 15, ty = tid >> 4;
    const int n0 = blockIdx.x * 64;
    const int m0 = blockIdx.y * 64;

    float acc[4][4] = {};
    for (int k0 = 0; k0 < 512; k0 += 32) {
        #pragma unroll
        for (int r2 = 0; r2 < 2; ++r2) {
            int row = (tid >> 3) + r2 * 32;
            int c4  = (tid & 7) * 4;
            *reinterpret_cast<float4*>(&As[row][c4]) =
                *reinterpret_cast<const float4*>(A + (size_t)(m0 + row) * 512 + k0 + c4);
        }
        #pragma unroll
        for (int r2 = 0; r2 < 2; ++r2) {
            int kk = (tid >> 4) + r2 * 16;
            int c4 = (tid & 15) * 4;
            *reinterpret_cast<float4*>(&Bs[kk][c4]) =
                *reinterpret_cast<const float4*>(B + (size_t)(k0 + kk) * 512 + n0 + c4);
        }
        __syncthreads();
        #pragma unroll
        for (int k = 0; k < 32; ++k) {
            float a0 = As[ty*4+0][k], a1 = As[ty*4+1][k];
            float a2 = As[ty*4+2][k], a3 = As[ty*4+3][k];
            float4 bv = *reinterpret_cast<const float4*>(&Bs[k][tx*4]);
            acc[0][0] += a0*bv.x; acc[0][1] += a0*bv.y; acc[0][2] += a0*bv.z; acc[0][3] += a0*bv.w;
            acc[1][0] += a1*bv.x; acc[1][1] += a1*bv.y; acc[1][2] += a1*bv.z; acc[1][3] += a1*bv.w;
            acc[2][0] += a2*bv.x; acc[2][1] += a2*bv.y; acc[2][2] += a2*bv.z; acc[2][3] += a2*bv.w;
            acc[3][0] += a3*bv.x; acc[3][1] += a3*bv.y; acc[3][2] += a3*bv.z; acc[3][3] += a3*bv.w;
        }
        __syncthreads();
    }
    const int c = n0 + tx * 4;
    #pragma unroll
    for (int ii = 0; ii < 4; ++ii) {
        int m = m0 + ty * 4 + ii;
        float4 v = make_float4(acc[ii][0], acc[ii][1], acc[ii][2], acc[ii][3]);
        *reinterpret_cast<float4*>(C + (size_t)m * 512 + c) = v;
    }
}

extern "C" void kernel_launch(void* const* d_in, const int* in_sizes, int n_in,
                              void* d_out, int out_size, void* d_ws, size_t ws_size,
                              hipStream_t stream) {
    const float* w    = (const float*)d_in[0];
    const float* r    = (const float*)d_in[1];
    const float* rwb  = (const float*)d_in[2];
    const float* rrb  = (const float*)d_in[3];
    const float* mems = (const float*)d_in[4];
    const float* Wqkv = (const float*)d_in[6];
    const float* Wr   = (const float*)d_in[7];
    const float* Wo   = (const float*)d_in[8];
    float* out = (float*)d_out;
    char*  wsb = (char*)d_ws;

    unsigned short* QW = (unsigned short*)(wsb + B_QW);
    unsigned short* QR = (unsigned short*)(wsb + B_QR);
    unsigned short* Kg = (unsigned short*)(wsb + B_K);
    unsigned short* VT = (unsigned short*)(wsb + B_VT);
    unsigned short* Rg = (unsigned short*)(wsb + B_R);
    float* AV  = (float*)(wsb + B_AV);
    float* ENT = (float*)(wsb + B_ENT);

    zpad_r<<<32, 256, 0, stream>>>(Rg);
    gemm_qkv<<<dim3(24, 256), 256, 0, stream>>>(mems, w, Wqkv, rwb, rrb, QW, QR, Kg, VT);
    gemm_r<<<dim3(8, 32), 256, 0, stream>>>(r, Wr, Rg);
    attn_mfma<<<dim3(16, 64), 256, 0, stream>>>(QW, QR, Kg, VT, Rg, AV, ENT);
    reduce_ent<<<1, 64, 0, stream>>>(ENT, out);
    gemm_out<<<dim3(8, 128), 256, 0, stream>>>(AV, Wo, out);
}

// Round 6
// 363.917 us; speedup vs baseline: 12.1272x; 1.7994x over previous
//
#include <hip/hip_runtime.h>
#include <hip/hip_bf16.h>

// Transformer-XL RelPartialLearnableMultiHeadAttn — round 6: all GEMMs on MFMA.
// convert (cast/transpose) -> gemm_mfma<0> QKV -> gemm_mfma<1> R -> attn_mfma
// (unchanged core, bf16 AV out) -> reduce_ent -> gemm_mfma<2> out-proj.

#define QLEN 1024
#define MLEN 1024
#define KLEN 2048
#define BSZ 8
#define DMODEL 512
#define NHEAD 8
#define DHEAD 64
#define SCALE 0.125f
#define RPAD 2176

// workspace byte offsets
#define B_QW   0u            // bf16 [bn][1024][64]
#define B_QR   8388608u      // bf16 [bn][1024][64]
#define B_K    16777216u     // bf16 [bn][2048][64]
#define B_VT   33554432u     // bf16 [bn][64][2048]
#define B_R    50331648u     // bf16 [n][2176][64]
#define B_AVB  52559872u     // bf16 [i*8+b][512]
#define B_ENT  60948480u     // f32  [bn][16]
#define B_ABF  60952576u     // bf16 [16384][512] cat(mems,w)
#define B_WQT  77729792u     // bf16 [1536][512]  W_qkv^T
#define B_RBF  79302656u     // bf16 [2048][512]  r
#define B_WRT  81399808u     // bf16 [512][512]   W_r^T
#define B_WOT  81924096u     // bf16 [512][512]   W_o^T

typedef short bf16x8 __attribute__((ext_vector_type(8)));
typedef float f32x4  __attribute__((ext_vector_type(4)));

__device__ __forceinline__ unsigned short f2bf(float f) {
    union { float f; unsigned int u; } v; v.f = f;
    unsigned int r = v.u + 0x7FFFu + ((v.u >> 16) & 1u);
    return (unsigned short)(r >> 16);
}

// ---- cast cat(mems,w) -> bf16 [16384][512] --------------------------------
__global__ __launch_bounds__(256) void cvt_cat(const float* __restrict__ mems,
                                               const float* __restrict__ w,
                                               unsigned short* __restrict__ Abf) {
    size_t e = ((size_t)blockIdx.x * 256 + threadIdx.x) * 8;
    int m = (int)(e >> 9), k = (int)(e & 511);
    int t = m >> 3, b = m & 7;
    const float* src = (t < MLEN) ? mems + ((size_t)t * 8 + b) * 512 + k
                                  : w    + ((size_t)(t - MLEN) * 8 + b) * 512 + k;
    float4 v0 = *reinterpret_cast<const float4*>(src);
    float4 v1 = *reinterpret_cast<const float4*>(src + 4);
    ushort4 o0, o1;
    o0.x = f2bf(v0.x); o0.y = f2bf(v0.y); o0.z = f2bf(v0.z); o0.w = f2bf(v0.w);
    o1.x = f2bf(v1.x); o1.y = f2bf(v1.y); o1.z = f2bf(v1.z); o1.w = f2bf(v1.w);
    *reinterpret_cast<ushort4*>(Abf + e)     = o0;
    *reinterpret_cast<ushort4*>(Abf + e + 4) = o1;
}

// ---- cast r -> bf16 [2048][512] -------------------------------------------
__global__ __launch_bounds__(256) void cvt_r(const float* __restrict__ r,
                                             unsigned short* __restrict__ rbf) {
    size_t e = ((size_t)blockIdx.x * 256 + threadIdx.x) * 8;
    float4 v0 = *reinterpret_cast<const float4*>(r + e);
    float4 v1 = *reinterpret_cast<const float4*>(r + e + 4);
    ushort4 o0, o1;
    o0.x = f2bf(v0.x); o0.y = f2bf(v0.y); o0.z = f2bf(v0.z); o0.w = f2bf(v0.w);
    o1.x = f2bf(v1.x); o1.y = f2bf(v1.y); o1.z = f2bf(v1.z); o1.w = f2bf(v1.w);
    *reinterpret_cast<ushort4*>(rbf + e)     = o0;
    *reinterpret_cast<ushort4*>(rbf + e + 4) = o1;
}

// ---- transpose+cast: S[R][C] f32 -> D[C][R] bf16 --------------------------
__global__ __launch_bounds__(256) void tcvt(const float* __restrict__ S,
                                            unsigned short* __restrict__ D,
                                            int R, int C) {
    __shared__ float t[32][33];
    int bx = blockIdx.x * 32;   // col base
    int by = blockIdx.y * 32;   // row base
    int x = threadIdx.x & 31, y = threadIdx.x >> 5;
    #pragma unroll
    for (int q = 0; q < 4; ++q)
        t[y + q * 8][x] = S[(size_t)(by + y + q * 8) * C + bx + x];
    __syncthreads();
    #pragma unroll
    for (int q = 0; q < 4; ++q)
        D[(size_t)(bx + y + q * 8) * R + by + x] = f2bf(t[x][y + q * 8]);
}

// ---- zero pad rows 2048..2175 of Rg ---------------------------------------
__global__ void zpad_r(unsigned short* __restrict__ Rg) {
    int idx = blockIdx.x * 256 + threadIdx.x;
    int n = idx >> 10, o = idx & 1023;
    uint4 z = make_uint4(0, 0, 0, 0);
    *reinterpret_cast<uint4*>(Rg + ((size_t)n * RPAD + KLEN) * 64 + o * 8) = z;
}

// ---------------------------------------------------------------------------
// bf16 MFMA GEMM: C[M][N] = A[M][512] @ Bt[N][512]^T. 128x128 tile, 4 waves.
// MODE 0: QKV epilogue (bias + QW/QR/K/VT scatter). MODE 1: -> Rg. MODE 2: f32 out.
// ---------------------------------------------------------------------------
template<int MODE>
__global__ __launch_bounds__(256) void gemm_mfma(const unsigned short* __restrict__ A,
                                                 const unsigned short* __restrict__ Bt,
                                                 const float* __restrict__ rwb,
                                                 const float* __restrict__ rrb,
                                                 unsigned short* __restrict__ QW,
                                                 unsigned short* __restrict__ QR,
                                                 unsigned short* __restrict__ Kg,
                                                 unsigned short* __restrict__ VT,
                                                 unsigned short* __restrict__ Rg,
                                                 float* __restrict__ Cout) {
    __shared__ unsigned short Als[128][72];
    __shared__ unsigned short Bls[128][72];
    const int tid = threadIdx.x;
    const int wv = tid >> 6, lane = tid & 63, lg = lane >> 4, lc = lane & 15;
    const int wr = wv >> 1, wc = wv & 1;
    const int n0 = blockIdx.x * 128;
    const int m0 = blockIdx.y * 128;

    f32x4 acc[4][4];
    #pragma unroll
    for (int mi = 0; mi < 4; ++mi)
        #pragma unroll
        for (int ni = 0; ni < 4; ++ni)
            acc[mi][ni] = (f32x4){0.f, 0.f, 0.f, 0.f};

    for (int k0 = 0; k0 < 512; k0 += 64) {
        __syncthreads();
        #pragma unroll
        for (int q = 0; q < 4; ++q) {
            int c = q * 256 + tid;
            int row = c >> 3, off = (c & 7) * 8;
            *reinterpret_cast<uint4*>(&Als[row][off]) =
                *reinterpret_cast<const uint4*>(A + (size_t)(m0 + row) * 512 + k0 + off);
            *reinterpret_cast<uint4*>(&Bls[row][off]) =
                *reinterpret_cast<const uint4*>(Bt + (size_t)(n0 + row) * 512 + k0 + off);
        }
        __syncthreads();
        #pragma unroll
        for (int kk = 0; kk < 2; ++kk) {
            bf16x8 af[4], bfr[4];
            #pragma unroll
            for (int mi = 0; mi < 4; ++mi)
                af[mi] = *reinterpret_cast<const bf16x8*>(&Als[64 * wr + 16 * mi + lc][32 * kk + lg * 8]);
            #pragma unroll
            for (int ni = 0; ni < 4; ++ni)
                bfr[ni] = *reinterpret_cast<const bf16x8*>(&Bls[64 * wc + 16 * ni + lc][32 * kk + lg * 8]);
            #pragma unroll
            for (int mi = 0; mi < 4; ++mi)
                #pragma unroll
                for (int ni = 0; ni < 4; ++ni)
                    acc[mi][ni] = __builtin_amdgcn_mfma_f32_16x16x32_bf16(af[mi], bfr[ni], acc[mi][ni], 0, 0, 0);
        }
    }

    #pragma unroll
    for (int mi = 0; mi < 4; ++mi) {
        #pragma unroll
        for (int ni = 0; ni < 4; ++ni) {
            const int n = n0 + 64 * wc + 16 * ni + lc;
            float bw = 0.f, br = 0.f;
            int region = 0, hn = 0, d = 0;
            if (MODE == 0) {
                region = n >> 9; int cr = n & 511; hn = cr >> 6; d = cr & 63;
                if (region == 0) { bw = rwb[hn * 64 + d]; br = rrb[hn * 64 + d]; }
            }
            #pragma unroll
            for (int reg = 0; reg < 4; ++reg) {
                const int m = m0 + 64 * wr + 16 * mi + lg * 4 + reg;
                const float val = acc[mi][ni][reg];
                if (MODE == 0) {
                    int t = m >> 3, b = m & 7, bn = b * 8 + hn;
                    if (region == 0) {
                        if (t >= MLEN) {
                            size_t base = ((size_t)bn * QLEN + (t - MLEN)) * 64 + d;
                            QW[base] = f2bf(val + bw);
                            QR[base] = f2bf(val + br);
                        }
                    } else if (region == 1) {
                        Kg[((size_t)bn * KLEN + t) * 64 + d] = f2bf(val);
                    } else {
                        VT[((size_t)bn * 64 + d) * KLEN + t] = f2bf(val);
                    }
                } else if (MODE == 1) {
                    Rg[((size_t)(n >> 6) * RPAD + m) * 64 + (n & 63)] = f2bf(val);
                } else {
                    Cout[(size_t)m * 512 + n] = val;
                }
            }
        }
    }
}

// ---------------------------------------------------------------------------
// MFMA attention (round-5 core, bf16 AV epilogue). grid (16 i-tiles, 64 bn).
// ---------------------------------------------------------------------------
__global__ __launch_bounds__(256) void attn_mfma(const unsigned short* __restrict__ QWg,
                                                 const unsigned short* __restrict__ QRg,
                                                 const unsigned short* __restrict__ Kg,
                                                 const unsigned short* __restrict__ VTg,
                                                 const unsigned short* __restrict__ Rg,
                                                 unsigned short* __restrict__ AVB,
                                                 float* __restrict__ ENT) {
    __shared__ unsigned short Klds[64][72];
    __shared__ unsigned short Rblds[128][72];
    __shared__ unsigned short Vtlds[64][72];
    __shared__ unsigned short Plds[64][72];
    __shared__ float Gscr[4][16][36];
    __shared__ float hred[4];

    const int tid = threadIdx.x;
    const int w = tid >> 6, lane = tid & 63, lg = lane >> 4, lc = lane & 15;
    const int i0 = blockIdx.x * 64;
    const int bn = blockIdx.y, b = bn >> 3, n = bn & 7;

    {
        const unsigned short* qwsrc = QWg + ((size_t)bn * QLEN + i0) * 64;
        const unsigned short* qrsrc = QRg + ((size_t)bn * QLEN + i0) * 64;
        #pragma unroll
        for (int q = 0; q < 2; ++q) {
            int idx = tid * 2 + q;
            int row = idx >> 3, c8 = (idx & 7) * 8;
            *reinterpret_cast<uint4*>(&Klds[row][c8])  = *reinterpret_cast<const uint4*>(qwsrc + row * 64 + c8);
            *reinterpret_cast<uint4*>(&Rblds[row][c8]) = *reinterpret_cast<const uint4*>(qrsrc + row * 64 + c8);
        }
    }
    __syncthreads();
    bf16x8 aqw[2], aqr[2];
    #pragma unroll
    for (int k = 0; k < 2; ++k) {
        aqw[k] = *reinterpret_cast<const bf16x8*>(&Klds[16 * w + lc][32 * k + lg * 8]);
        aqr[k] = *reinterpret_cast<const bf16x8*>(&Rblds[16 * w + lc][32 * k + lg * 8]);
    }

    f32x4 Ofr[4];
    #pragma unroll
    for (int t = 0; t < 4; ++t) Ofr[t] = (f32x4){0.f, 0.f, 0.f, 0.f};
    float mreg[4] = {-1e30f, -1e30f, -1e30f, -1e30f};
    float lreg[4] = {0.f, 0.f, 0.f, 0.f};
    float treg[4] = {0.f, 0.f, 0.f, 0.f};

    const int nj = (i0 >> 6) + 17;
    const unsigned short* kbase = Kg  + (size_t)bn * KLEN * 64;
    const unsigned short* vbase = VTg + (size_t)bn * 64 * KLEN;
    const unsigned short* rbase = Rg  + (size_t)n * RPAD * 64 + (size_t)(960 - i0) * 64;

    for (int jt = 0; jt < nj; ++jt) {
        const int j0 = jt * 64;
        __syncthreads();
        #pragma unroll
        for (int q = 0; q < 2; ++q) {
            int idx = tid * 2 + q, row = idx >> 3, c8 = (idx & 7) * 8;
            *reinterpret_cast<uint4*>(&Klds[row][c8]) =
                *reinterpret_cast<const uint4*>(kbase + (size_t)(j0 + row) * 64 + c8);
            *reinterpret_cast<uint4*>(&Vtlds[row][c8]) =
                *reinterpret_cast<const uint4*>(vbase + (size_t)row * KLEN + j0 + c8);
        }
        #pragma unroll
        for (int q = 0; q < 4; ++q) {
            int idx = tid * 4 + q, row = idx >> 3, c8 = (idx & 7) * 8;
            *reinterpret_cast<uint4*>(&Rblds[row][c8]) =
                *reinterpret_cast<const uint4*>(rbase + (size_t)(j0 + row) * 64 + c8);
        }
        __syncthreads();

        f32x4 sfr[4];
        #pragma unroll
        for (int bj = 0; bj < 4; ++bj) {
            f32x4 acc = (f32x4){0.f, 0.f, 0.f, 0.f};
            #pragma unroll
            for (int k = 0; k < 2; ++k) {
                bf16x8 bk = *reinterpret_cast<const bf16x8*>(&Klds[16 * bj + lc][32 * k + lg * 8]);
                acc = __builtin_amdgcn_mfma_f32_16x16x32_bf16(aqw[k], bk, acc, 0, 0, 0);
            }
            f32x4 g0 = (f32x4){0.f, 0.f, 0.f, 0.f}, g1 = (f32x4){0.f, 0.f, 0.f, 0.f};
            const int obase = 16 * (bj - w) + 48;
            #pragma unroll
            for (int k = 0; k < 2; ++k) {
                bf16x8 br0 = *reinterpret_cast<const bf16x8*>(&Rblds[obase + lc][32 * k + lg * 8]);
                bf16x8 br1 = *reinterpret_cast<const bf16x8*>(&Rblds[obase + 16 + lc][32 * k + lg * 8]);
                g0 = __builtin_amdgcn_mfma_f32_16x16x32_bf16(aqr[k], br0, g0, 0, 0, 0);
                g1 = __builtin_amdgcn_mfma_f32_16x16x32_bf16(aqr[k], br1, g1, 0, 0, 0);
            }
            #pragma unroll
            for (int reg = 0; reg < 4; ++reg) {
                Gscr[w][lg * 4 + reg][lc]      = g0[reg];
                Gscr[w][lg * 4 + reg][16 + lc] = g1[reg];
            }
            asm volatile("s_waitcnt lgkmcnt(0)" ::: "memory");
            __builtin_amdgcn_sched_barrier(0);
            #pragma unroll
            for (int reg = 0; reg < 4; ++reg) {
                int r = lg * 4 + reg;
                int ii = 16 * w + r;
                int jj = 16 * bj + lc;
                float g = Gscr[w][r][lc - r + 15];
                float s = (acc[reg] + g) * SCALE;
                bool valid = (j0 + jj) <= (i0 + ii + MLEN);
                sfr[bj][reg] = valid ? s : -1e30f;
            }
        }

        float pf[4][4];
        #pragma unroll
        for (int reg = 0; reg < 4; ++reg) {
            float gmax = fmaxf(fmaxf(sfr[0][reg], sfr[1][reg]), fmaxf(sfr[2][reg], sfr[3][reg]));
            gmax = fmaxf(gmax, __shfl_xor(gmax, 1));
            gmax = fmaxf(gmax, __shfl_xor(gmax, 2));
            gmax = fmaxf(gmax, __shfl_xor(gmax, 4));
            gmax = fmaxf(gmax, __shfl_xor(gmax, 8));
            float mo = mreg[reg];
            float mn = fmaxf(mo, gmax);
            float le = 0.f, te = 0.f;
            #pragma unroll
            for (int bj = 0; bj < 4; ++bj) {
                float e = __expf(sfr[bj][reg] - mn);
                le += e; te += e * sfr[bj][reg];
                pf[bj][reg] = e;
            }
            le += __shfl_xor(le, 1); le += __shfl_xor(le, 2);
            le += __shfl_xor(le, 4); le += __shfl_xor(le, 8);
            te += __shfl_xor(te, 1); te += __shfl_xor(te, 2);
            te += __shfl_xor(te, 4); te += __shfl_xor(te, 8);
            float fac = __expf(mo - mn);
            lreg[reg] = lreg[reg] * fac + le;
            treg[reg] = treg[reg] * fac + te;
            mreg[reg] = mn;
            Ofr[0][reg] *= fac; Ofr[1][reg] *= fac;
            Ofr[2][reg] *= fac; Ofr[3][reg] *= fac;
            int r = lg * 4 + reg;
            #pragma unroll
            for (int bj = 0; bj < 4; ++bj)
                Plds[16 * w + r][16 * bj + lc] = f2bf(pf[bj][reg]);
        }
        asm volatile("s_waitcnt lgkmcnt(0)" ::: "memory");
        __builtin_amdgcn_sched_barrier(0);

        #pragma unroll
        for (int k = 0; k < 2; ++k) {
            bf16x8 ap = *reinterpret_cast<const bf16x8*>(&Plds[16 * w + lc][32 * k + lg * 8]);
            Ofr[0] = __builtin_amdgcn_mfma_f32_16x16x32_bf16(ap,
                *reinterpret_cast<const bf16x8*>(&Vtlds[ 0 + lc][32 * k + lg * 8]), Ofr[0], 0, 0, 0);
            Ofr[1] = __builtin_amdgcn_mfma_f32_16x16x32_bf16(ap,
                *reinterpret_cast<const bf16x8*>(&Vtlds[16 + lc][32 * k + lg * 8]), Ofr[1], 0, 0, 0);
            Ofr[2] = __builtin_amdgcn_mfma_f32_16x16x32_bf16(ap,
                *reinterpret_cast<const bf16x8*>(&Vtlds[32 + lc][32 * k + lg * 8]), Ofr[2], 0, 0, 0);
            Ofr[3] = __builtin_amdgcn_mfma_f32_16x16x32_bf16(ap,
                *reinterpret_cast<const bf16x8*>(&Vtlds[48 + lc][32 * k + lg * 8]), Ofr[3], 0, 0, 0);
        }
    }

    #pragma unroll
    for (int reg = 0; reg < 4; ++reg) {
        int i = i0 + 16 * w + lg * 4 + reg;
        float inv = 1.f / lreg[reg];
        unsigned short* dst = AVB + ((size_t)i * BSZ + b) * DMODEL + n * 64 + lc;
        dst[ 0] = f2bf(Ofr[0][reg] * inv);
        dst[16] = f2bf(Ofr[1][reg] * inv);
        dst[32] = f2bf(Ofr[2][reg] * inv);
        dst[48] = f2bf(Ofr[3][reg] * inv);
    }

    float h = 0.f;
    if (lc == 0) {
        #pragma unroll
        for (int reg = 0; reg < 4; ++reg)
            h += mreg[reg] + __logf(lreg[reg]) - treg[reg] / lreg[reg];
    }
    h += __shfl_xor(h, 1);  h += __shfl_xor(h, 2);  h += __shfl_xor(h, 4);
    h += __shfl_xor(h, 8);  h += __shfl_xor(h, 16); h += __shfl_xor(h, 32);
    if (lane == 0) hred[w] = h;
    __syncthreads();
    if (tid == 0) ENT[bn * 16 + (i0 >> 6)] = hred[0] + hred[1] + hred[2] + hred[3];
}

__global__ void reduce_ent(const float* __restrict__ ent, float* __restrict__ out) {
    int n = threadIdx.x;
    if (n < NHEAD) {
        float s = 0.f;
        for (int b = 0; b < BSZ; ++b)
            for (int it = 0; it < 16; ++it)
                s += ent[(b * NHEAD + n) * 16 + it];
        out[(size_t)QLEN * BSZ * DMODEL + n] = s / (float)(QLEN * BSZ);
    }
}

extern "C" void kernel_launch(void* const* d_in, const int* in_sizes, int n_in,
                              void* d_out, int out_size, void* d_ws, size_t ws_size,
                              hipStream_t stream) {
    const float* w    = (const float*)d_in[0];
    const float* r    = (const float*)d_in[1];
    const float* rwb  = (const float*)d_in[2];
    const float* rrb  = (const float*)d_in[3];
    const float* mems = (const float*)d_in[4];
    const float* Wqkv = (const float*)d_in[6];
    const float* Wr   = (const float*)d_in[7];
    const float* Wo   = (const float*)d_in[8];
    float* out = (float*)d_out;
    char*  wsb = (char*)d_ws;

    unsigned short* QW  = (unsigned short*)(wsb + B_QW);
    unsigned short* QR  = (unsigned short*)(wsb + B_QR);
    unsigned short* Kg  = (unsigned short*)(wsb + B_K);
    unsigned short* VT  = (unsigned short*)(wsb + B_VT);
    unsigned short* Rg  = (unsigned short*)(wsb + B_R);
    unsigned short* AVB = (unsigned short*)(wsb + B_AVB);
    float* ENT = (float*)(wsb + B_ENT);
    unsigned short* ABF = (unsigned short*)(wsb + B_ABF);
    unsigned short* WQT = (unsigned short*)(wsb + B_WQT);
    unsigned short* RBF = (unsigned short*)(wsb + B_RBF);
    unsigned short* WRT = (unsigned short*)(wsb + B_WRT);
    unsigned short* WOT = (unsigned short*)(wsb + B_WOT);

    // converts
    cvt_cat<<<4096, 256, 0, stream>>>(mems, w, ABF);
    cvt_r<<<512, 256, 0, stream>>>(r, RBF);
    tcvt<<<dim3(48, 16), 256, 0, stream>>>(Wqkv, WQT, 512, 1536);
    tcvt<<<dim3(16, 16), 256, 0, stream>>>(Wr, WRT, 512, 512);
    tcvt<<<dim3(16, 16), 256, 0, stream>>>(Wo, WOT, 512, 512);
    zpad_r<<<32, 256, 0, stream>>>(Rg);

    // projections (MFMA)
    gemm_mfma<0><<<dim3(12, 128), 256, 0, stream>>>(ABF, WQT, rwb, rrb, QW, QR, Kg, VT, nullptr, nullptr);
    gemm_mfma<1><<<dim3(4, 16), 256, 0, stream>>>(RBF, WRT, nullptr, nullptr,
                                                  nullptr, nullptr, nullptr, nullptr, Rg, nullptr);

    // attention + entropy
    attn_mfma<<<dim3(16, 64), 256, 0, stream>>>(QW, QR, Kg, VT, Rg, AVB, ENT);
    reduce_ent<<<1, 64, 0, stream>>>(ENT, out);

    // output projection (MFMA)
    gemm_mfma<2><<<dim3(4, 64), 256, 0, stream>>>(AVB, WOT, nullptr, nullptr,
                                                  nullptr, nullptr, nullptr, nullptr, nullptr, out);
}

// Round 7
// 341.429 us; speedup vs baseline: 12.9259x; 1.0659x over previous
//
#include <hip/hip_runtime.h>
#include <hip/hip_bf16.h>

// Transformer-XL RelPartialLearnableMultiHeadAttn — round 7: attn LDS overhaul.
// XOR-swizzled LDS tiles (conflict-free ds_read_b128), shfl-based rel-shift
// diagonal gather (no Gscr round-trip), deferred l/t reduction, 40KB LDS ->
// 4 blocks/CU. GEMMs/converts unchanged from round 6.

#define QLEN 1024
#define MLEN 1024
#define KLEN 2048
#define BSZ 8
#define DMODEL 512
#define NHEAD 8
#define DHEAD 64
#define SCALE 0.125f
#define RPAD 2176

// workspace byte offsets
#define B_QW   0u            // bf16 [bn][1024][64]
#define B_QR   8388608u      // bf16 [bn][1024][64]
#define B_K    16777216u     // bf16 [bn][2048][64]
#define B_VT   33554432u     // bf16 [bn][64][2048]
#define B_R    50331648u     // bf16 [n][2176][64]
#define B_AVB  52559872u     // bf16 [i*8+b][512]
#define B_ENT  60948480u     // f32  [bn][16]
#define B_ABF  60952576u     // bf16 [16384][512] cat(mems,w)
#define B_WQT  77729792u     // bf16 [1536][512]  W_qkv^T
#define B_RBF  79302656u     // bf16 [2048][512]  r
#define B_WRT  81399808u     // bf16 [512][512]   W_r^T
#define B_WOT  81924096u     // bf16 [512][512]   W_o^T

typedef short bf16x8 __attribute__((ext_vector_type(8)));
typedef float f32x4  __attribute__((ext_vector_type(4)));

// XOR-swizzle within a [row][64]bf16 (128B-row) tile: chunk ^= row&7
#define SWZ(row, byte) ((((row) << 7) + (((((byte) >> 4) ^ ((row) & 7)) << 4)) + ((byte) & 15)))

__device__ __forceinline__ unsigned short f2bf(float f) {
    union { float f; unsigned int u; } v; v.f = f;
    unsigned int r = v.u + 0x7FFFu + ((v.u >> 16) & 1u);
    return (unsigned short)(r >> 16);
}

// ---- cast cat(mems,w) -> bf16 [16384][512] --------------------------------
__global__ __launch_bounds__(256) void cvt_cat(const float* __restrict__ mems,
                                               const float* __restrict__ w,
                                               unsigned short* __restrict__ Abf) {
    size_t e = ((size_t)blockIdx.x * 256 + threadIdx.x) * 8;
    int m = (int)(e >> 9), k = (int)(e & 511);
    int t = m >> 3, b = m & 7;
    const float* src = (t < MLEN) ? mems + ((size_t)t * 8 + b) * 512 + k
                                  : w    + ((size_t)(t - MLEN) * 8 + b) * 512 + k;
    float4 v0 = *reinterpret_cast<const float4*>(src);
    float4 v1 = *reinterpret_cast<const float4*>(src + 4);
    ushort4 o0, o1;
    o0.x = f2bf(v0.x); o0.y = f2bf(v0.y); o0.z = f2bf(v0.z); o0.w = f2bf(v0.w);
    o1.x = f2bf(v1.x); o1.y = f2bf(v1.y); o1.z = f2bf(v1.z); o1.w = f2bf(v1.w);
    *reinterpret_cast<ushort4*>(Abf + e)     = o0;
    *reinterpret_cast<ushort4*>(Abf + e + 4) = o1;
}

// ---- cast r -> bf16 [2048][512] -------------------------------------------
__global__ __launch_bounds__(256) void cvt_r(const float* __restrict__ r,
                                             unsigned short* __restrict__ rbf) {
    size_t e = ((size_t)blockIdx.x * 256 + threadIdx.x) * 8;
    float4 v0 = *reinterpret_cast<const float4*>(r + e);
    float4 v1 = *reinterpret_cast<const float4*>(r + e + 4);
    ushort4 o0, o1;
    o0.x = f2bf(v0.x); o0.y = f2bf(v0.y); o0.z = f2bf(v0.z); o0.w = f2bf(v0.w);
    o1.x = f2bf(v1.x); o1.y = f2bf(v1.y); o1.z = f2bf(v1.z); o1.w = f2bf(v1.w);
    *reinterpret_cast<ushort4*>(rbf + e)     = o0;
    *reinterpret_cast<ushort4*>(rbf + e + 4) = o1;
}

// ---- transpose+cast: S[R][C] f32 -> D[C][R] bf16 --------------------------
__global__ __launch_bounds__(256) void tcvt(const float* __restrict__ S,
                                            unsigned short* __restrict__ D,
                                            int R, int C) {
    __shared__ float t[32][33];
    int bx = blockIdx.x * 32;
    int by = blockIdx.y * 32;
    int x = threadIdx.x & 31, y = threadIdx.x >> 5;
    #pragma unroll
    for (int q = 0; q < 4; ++q)
        t[y + q * 8][x] = S[(size_t)(by + y + q * 8) * C + bx + x];
    __syncthreads();
    #pragma unroll
    for (int q = 0; q < 4; ++q)
        D[(size_t)(bx + y + q * 8) * R + by + x] = f2bf(t[x][y + q * 8]);
}

// ---- zero pad rows 2048..2175 of Rg ---------------------------------------
__global__ void zpad_r(unsigned short* __restrict__ Rg) {
    int idx = blockIdx.x * 256 + threadIdx.x;
    int n = idx >> 10, o = idx & 1023;
    uint4 z = make_uint4(0, 0, 0, 0);
    *reinterpret_cast<uint4*>(Rg + ((size_t)n * RPAD + KLEN) * 64 + o * 8) = z;
}

// ---------------------------------------------------------------------------
// bf16 MFMA GEMM: C[M][N] = A[M][512] @ Bt[N][512]^T. 128x128 tile, 4 waves.
// ---------------------------------------------------------------------------
template<int MODE>
__global__ __launch_bounds__(256) void gemm_mfma(const unsigned short* __restrict__ A,
                                                 const unsigned short* __restrict__ Bt,
                                                 const float* __restrict__ rwb,
                                                 const float* __restrict__ rrb,
                                                 unsigned short* __restrict__ QW,
                                                 unsigned short* __restrict__ QR,
                                                 unsigned short* __restrict__ Kg,
                                                 unsigned short* __restrict__ VT,
                                                 unsigned short* __restrict__ Rg,
                                                 float* __restrict__ Cout) {
    __shared__ unsigned short Als[128][72];
    __shared__ unsigned short Bls[128][72];
    const int tid = threadIdx.x;
    const int wv = tid >> 6, lane = tid & 63, lg = lane >> 4, lc = lane & 15;
    const int wr = wv >> 1, wc = wv & 1;
    const int n0 = blockIdx.x * 128;
    const int m0 = blockIdx.y * 128;

    f32x4 acc[4][4];
    #pragma unroll
    for (int mi = 0; mi < 4; ++mi)
        #pragma unroll
        for (int ni = 0; ni < 4; ++ni)
            acc[mi][ni] = (f32x4){0.f, 0.f, 0.f, 0.f};

    for (int k0 = 0; k0 < 512; k0 += 64) {
        __syncthreads();
        #pragma unroll
        for (int q = 0; q < 4; ++q) {
            int c = q * 256 + tid;
            int row = c >> 3, off = (c & 7) * 8;
            *reinterpret_cast<uint4*>(&Als[row][off]) =
                *reinterpret_cast<const uint4*>(A + (size_t)(m0 + row) * 512 + k0 + off);
            *reinterpret_cast<uint4*>(&Bls[row][off]) =
                *reinterpret_cast<const uint4*>(Bt + (size_t)(n0 + row) * 512 + k0 + off);
        }
        __syncthreads();
        #pragma unroll
        for (int kk = 0; kk < 2; ++kk) {
            bf16x8 af[4], bfr[4];
            #pragma unroll
            for (int mi = 0; mi < 4; ++mi)
                af[mi] = *reinterpret_cast<const bf16x8*>(&Als[64 * wr + 16 * mi + lc][32 * kk + lg * 8]);
            #pragma unroll
            for (int ni = 0; ni < 4; ++ni)
                bfr[ni] = *reinterpret_cast<const bf16x8*>(&Bls[64 * wc + 16 * ni + lc][32 * kk + lg * 8]);
            #pragma unroll
            for (int mi = 0; mi < 4; ++mi)
                #pragma unroll
                for (int ni = 0; ni < 4; ++ni)
                    acc[mi][ni] = __builtin_amdgcn_mfma_f32_16x16x32_bf16(af[mi], bfr[ni], acc[mi][ni], 0, 0, 0);
        }
    }

    #pragma unroll
    for (int mi = 0; mi < 4; ++mi) {
        #pragma unroll
        for (int ni = 0; ni < 4; ++ni) {
            const int n = n0 + 64 * wc + 16 * ni + lc;
            float bw = 0.f, br = 0.f;
            int region = 0, hn = 0, d = 0;
            if (MODE == 0) {
                region = n >> 9; int cr = n & 511; hn = cr >> 6; d = cr & 63;
                if (region == 0) { bw = rwb[hn * 64 + d]; br = rrb[hn * 64 + d]; }
            }
            #pragma unroll
            for (int reg = 0; reg < 4; ++reg) {
                const int m = m0 + 64 * wr + 16 * mi + lg * 4 + reg;
                const float val = acc[mi][ni][reg];
                if (MODE == 0) {
                    int t = m >> 3, b = m & 7, bn = b * 8 + hn;
                    if (region == 0) {
                        if (t >= MLEN) {
                            size_t base = ((size_t)bn * QLEN + (t - MLEN)) * 64 + d;
                            QW[base] = f2bf(val + bw);
                            QR[base] = f2bf(val + br);
                        }
                    } else if (region == 1) {
                        Kg[((size_t)bn * KLEN + t) * 64 + d] = f2bf(val);
                    } else {
                        VT[((size_t)bn * 64 + d) * KLEN + t] = f2bf(val);
                    }
                } else if (MODE == 1) {
                    Rg[((size_t)(n >> 6) * RPAD + m) * 64 + (n & 63)] = f2bf(val);
                } else {
                    Cout[(size_t)m * 512 + n] = val;
                }
            }
        }
    }
}

// ---------------------------------------------------------------------------
// MFMA attention, swizzled LDS. grid (16 i-tiles, 64 bn), 4 waves.
// ---------------------------------------------------------------------------
__global__ __launch_bounds__(256, 4) void attn_mfma(const unsigned short* __restrict__ QWg,
                                                    const unsigned short* __restrict__ QRg,
                                                    const unsigned short* __restrict__ Kg,
                                                    const unsigned short* __restrict__ VTg,
                                                    const unsigned short* __restrict__ Rg,
                                                    unsigned short* __restrict__ AVB,
                                                    float* __restrict__ ENT) {
    __shared__ __attribute__((aligned(16))) unsigned short Klds[64 * 64];    //  8 KB
    __shared__ __attribute__((aligned(16))) unsigned short Rblds[128 * 64];  // 16 KB
    __shared__ __attribute__((aligned(16))) unsigned short Vtlds[64 * 64];   //  8 KB
    __shared__ __attribute__((aligned(16))) unsigned short Plds[64 * 64];    //  8 KB

    const int tid = threadIdx.x;
    const int w = tid >> 6, lane = tid & 63, lg = lane >> 4, lc = lane & 15;
    const int i0 = blockIdx.x * 64;
    const int bn = blockIdx.y, b = bn >> 3, n = bn & 7;

    // ---- stage QW/QR i-tiles (into Klds/Rblds) and pull persistent A-frags
    {
        const unsigned short* qwsrc = QWg + ((size_t)bn * QLEN + i0) * 64;
        const unsigned short* qrsrc = QRg + ((size_t)bn * QLEN + i0) * 64;
        #pragma unroll
        for (int q = 0; q < 2; ++q) {
            int ci = q * 256 + tid;
            int row = ci >> 3, ch = ci & 7;
            *reinterpret_cast<uint4*>((char*)Klds + SWZ(row, ch * 16)) =
                *reinterpret_cast<const uint4*>(qwsrc + (size_t)row * 64 + ch * 8);
            *reinterpret_cast<uint4*>((char*)Rblds + SWZ(row, ch * 16)) =
                *reinterpret_cast<const uint4*>(qrsrc + (size_t)row * 64 + ch * 8);
        }
    }
    __syncthreads();
    bf16x8 aqw[2], aqr[2];
    #pragma unroll
    for (int k = 0; k < 2; ++k) {
        aqw[k] = *reinterpret_cast<const bf16x8*>((const char*)Klds + SWZ(16 * w + lc, 64 * k + 16 * lg));
        aqr[k] = *reinterpret_cast<const bf16x8*>((const char*)Rblds + SWZ(16 * w + lc, 64 * k + 16 * lg));
    }

    f32x4 Ofr[4];
    #pragma unroll
    for (int t = 0; t < 4; ++t) Ofr[t] = (f32x4){0.f, 0.f, 0.f, 0.f};
    float mreg[4] = {-1e30f, -1e30f, -1e30f, -1e30f};
    float lpart[4] = {0.f, 0.f, 0.f, 0.f};   // per-lane partials (4 cols each)
    float tpart[4] = {0.f, 0.f, 0.f, 0.f};

    const int nj = (i0 >> 6) + 17;
    const unsigned short* kbase = Kg  + (size_t)bn * KLEN * 64;
    const unsigned short* vbase = VTg + (size_t)bn * 64 * KLEN;
    const unsigned short* rbase = Rg  + (size_t)n * RPAD * 64 + (size_t)(960 - i0) * 64;

    for (int jt = 0; jt < nj; ++jt) {
        const int j0 = jt * 64;
        __syncthreads();
        // ---- stage K, Vt (512 chunks each), Rb (1024 chunks), swizzled ----
        #pragma unroll
        for (int q = 0; q < 2; ++q) {
            int ci = q * 256 + tid;
            int row = ci >> 3, ch = ci & 7;
            *reinterpret_cast<uint4*>((char*)Klds + SWZ(row, ch * 16)) =
                *reinterpret_cast<const uint4*>(kbase + (size_t)(j0 + row) * 64 + ch * 8);
            *reinterpret_cast<uint4*>((char*)Vtlds + SWZ(row, ch * 16)) =
                *reinterpret_cast<const uint4*>(vbase + (size_t)row * KLEN + j0 + ch * 8);
        }
        #pragma unroll
        for (int q = 0; q < 4; ++q) {
            int ci = q * 256 + tid;
            int row = ci >> 3, ch = ci & 7;
            *reinterpret_cast<uint4*>((char*)Rblds + SWZ(row, ch * 16)) =
                *reinterpret_cast<const uint4*>(rbase + (size_t)(j0 + row) * 64 + ch * 8);
        }
        __syncthreads();

        // ---- scores: AC (MFMA) + banded BD (MFMA + shfl diag gather) ----
        f32x4 sfr[4];
        #pragma unroll
        for (int bj = 0; bj < 4; ++bj) {
            f32x4 acc = (f32x4){0.f, 0.f, 0.f, 0.f};
            #pragma unroll
            for (int k = 0; k < 2; ++k) {
                bf16x8 bk = *reinterpret_cast<const bf16x8*>((const char*)Klds + SWZ(16 * bj + lc, 64 * k + 16 * lg));
                acc = __builtin_amdgcn_mfma_f32_16x16x32_bf16(aqw[k], bk, acc, 0, 0, 0);
            }
            f32x4 g0 = (f32x4){0.f, 0.f, 0.f, 0.f}, g1 = (f32x4){0.f, 0.f, 0.f, 0.f};
            const int obase = 16 * (bj - w) + 48;
            #pragma unroll
            for (int k = 0; k < 2; ++k) {
                bf16x8 br0 = *reinterpret_cast<const bf16x8*>((const char*)Rblds + SWZ(obase + lc, 64 * k + 16 * lg));
                bf16x8 br1 = *reinterpret_cast<const bf16x8*>((const char*)Rblds + SWZ(obase + 16 + lc, 64 * k + 16 * lg));
                g0 = __builtin_amdgcn_mfma_f32_16x16x32_bf16(aqr[k], br0, g0, 0, 0, 0);
                g1 = __builtin_amdgcn_mfma_f32_16x16x32_bf16(aqr[k], br1, g1, 0, 0, 0);
            }
            // diag gather: S[r][lc] += G[r][lc - r + 15]  (g0: cols 0..15, g1: 16..31)
            #pragma unroll
            for (int reg = 0; reg < 4; ++reg) {
                int r = lg * 4 + reg;
                int srcl = (lane & 48) | ((lc - r + 15) & 15);
                float s0 = __shfl(g0[reg], srcl, 64);
                float s1 = __shfl(g1[reg], srcl, 64);
                float g = (lc <= r) ? s0 : s1;
                sfr[bj][reg] = (acc[reg] + g) * SCALE;
            }
        }
        if (jt == nj - 1) {   // only the last j-tile can be masked
            #pragma unroll
            for (int bj = 0; bj < 4; ++bj)
                #pragma unroll
                for (int reg = 0; reg < 4; ++reg) {
                    int ii = 16 * w + lg * 4 + reg;
                    int jj = 16 * bj + lc;
                    if (j0 + jj > i0 + ii + MLEN) sfr[bj][reg] = -1e30f;
                }
        }

        // ---- online softmax: shared max, per-lane l/t partials ----
        #pragma unroll
        for (int reg = 0; reg < 4; ++reg) {
            float gmax = fmaxf(fmaxf(sfr[0][reg], sfr[1][reg]), fmaxf(sfr[2][reg], sfr[3][reg]));
            gmax = fmaxf(gmax, __shfl_xor(gmax, 1));
            gmax = fmaxf(gmax, __shfl_xor(gmax, 2));
            gmax = fmaxf(gmax, __shfl_xor(gmax, 4));
            gmax = fmaxf(gmax, __shfl_xor(gmax, 8));
            float mo = mreg[reg], mn = fmaxf(mo, gmax);
            float fac = __expf(mo - mn);
            float le = 0.f, te = 0.f;
            int r = lg * 4 + reg;
            #pragma unroll
            for (int bj = 0; bj < 4; ++bj) {
                float e = __expf(sfr[bj][reg] - mn);
                le += e; te += e * sfr[bj][reg];
                *reinterpret_cast<unsigned short*>((char*)Plds + SWZ(16 * w + r, 2 * (16 * bj + lc))) = f2bf(e);
            }
            lpart[reg] = lpart[reg] * fac + le;
            tpart[reg] = tpart[reg] * fac + te;
            mreg[reg] = mn;
            Ofr[0][reg] *= fac; Ofr[1][reg] *= fac;
            Ofr[2][reg] *= fac; Ofr[3][reg] *= fac;
        }
        asm volatile("s_waitcnt lgkmcnt(0)" ::: "memory");
        __builtin_amdgcn_sched_barrier(0);

        // ---- PV ----
        #pragma unroll
        for (int k = 0; k < 2; ++k) {
            bf16x8 ap = *reinterpret_cast<const bf16x8*>((const char*)Plds + SWZ(16 * w + lc, 64 * k + 16 * lg));
            Ofr[0] = __builtin_amdgcn_mfma_f32_16x16x32_bf16(ap,
                *reinterpret_cast<const bf16x8*>((const char*)Vtlds + SWZ( 0 + lc, 64 * k + 16 * lg)), Ofr[0], 0, 0, 0);
            Ofr[1] = __builtin_amdgcn_mfma_f32_16x16x32_bf16(ap,
                *reinterpret_cast<const bf16x8*>((const char*)Vtlds + SWZ(16 + lc, 64 * k + 16 * lg)), Ofr[1], 0, 0, 0);
            Ofr[2] = __builtin_amdgcn_mfma_f32_16x16x32_bf16(ap,
                *reinterpret_cast<const bf16x8*>((const char*)Vtlds + SWZ(32 + lc, 64 * k + 16 * lg)), Ofr[2], 0, 0, 0);
            Ofr[3] = __builtin_amdgcn_mfma_f32_16x16x32_bf16(ap,
                *reinterpret_cast<const bf16x8*>((const char*)Vtlds + SWZ(48 + lc, 64 * k + 16 * lg)), Ofr[3], 0, 0, 0);
        }
    }

    // ---- final l/t reduction across the 16 lc lanes ----
    float lred[4], tred[4];
    #pragma unroll
    for (int reg = 0; reg < 4; ++reg) {
        float l = lpart[reg], t = tpart[reg];
        l += __shfl_xor(l, 1); l += __shfl_xor(l, 2); l += __shfl_xor(l, 4); l += __shfl_xor(l, 8);
        t += __shfl_xor(t, 1); t += __shfl_xor(t, 2); t += __shfl_xor(t, 4); t += __shfl_xor(t, 8);
        lred[reg] = l; tred[reg] = t;
    }

    // ---- normalize + write attn_vec (bf16) ----
    #pragma unroll
    for (int reg = 0; reg < 4; ++reg) {
        int i = i0 + 16 * w + lg * 4 + reg;
        float inv = 1.f / lred[reg];
        unsigned short* dst = AVB + ((size_t)i * BSZ + b) * DMODEL + n * 64 + lc;
        dst[ 0] = f2bf(Ofr[0][reg] * inv);
        dst[16] = f2bf(Ofr[1][reg] * inv);
        dst[32] = f2bf(Ofr[2][reg] * inv);
        dst[48] = f2bf(Ofr[3][reg] * inv);
    }

    // ---- entropy partial (alias hred into dead Klds behind a barrier) ----
    float h = 0.f;
    if (lc == 0) {
        #pragma unroll
        for (int reg = 0; reg < 4; ++reg)
            h += mreg[reg] + __logf(lred[reg]) - tred[reg] / lred[reg];
    }
    h += __shfl_xor(h, 1);  h += __shfl_xor(h, 2);  h += __shfl_xor(h, 4);
    h += __shfl_xor(h, 8);  h += __shfl_xor(h, 16); h += __shfl_xor(h, 32);
    __syncthreads();
    float* hred = reinterpret_cast<float*>(Klds);
    if (lane == 0) hred[w] = h;
    __syncthreads();
    if (tid == 0) ENT[bn * 16 + (i0 >> 6)] = hred[0] + hred[1] + hred[2] + hred[3];
}

__global__ void reduce_ent(const float* __restrict__ ent, float* __restrict__ out) {
    int n = threadIdx.x;
    if (n < NHEAD) {
        float s = 0.f;
        for (int b = 0; b < BSZ; ++b)
            for (int it = 0; it < 16; ++it)
                s += ent[(b * NHEAD + n) * 16 + it];
        out[(size_t)QLEN * BSZ * DMODEL + n] = s / (float)(QLEN * BSZ);
    }
}

extern "C" void kernel_launch(void* const* d_in, const int* in_sizes, int n_in,
                              void* d_out, int out_size, void* d_ws, size_t ws_size,
                              hipStream_t stream) {
    const float* w    = (const float*)d_in[0];
    const float* r    = (const float*)d_in[1];
    const float* rwb  = (const float*)d_in[2];
    const float* rrb  = (const float*)d_in[3];
    const float* mems = (const float*)d_in[4];
    const float* Wqkv = (const float*)d_in[6];
    const float* Wr   = (const float*)d_in[7];
    const float* Wo   = (const float*)d_in[8];
    float* out = (float*)d_out;
    char*  wsb = (char*)d_ws;

    unsigned short* QW  = (unsigned short*)(wsb + B_QW);
    unsigned short* QR  = (unsigned short*)(wsb + B_QR);
    unsigned short* Kg  = (unsigned short*)(wsb + B_K);
    unsigned short* VT  = (unsigned short*)(wsb + B_VT);
    unsigned short* Rg  = (unsigned short*)(wsb + B_R);
    unsigned short* AVB = (unsigned short*)(wsb + B_AVB);
    float* ENT = (float*)(wsb + B_ENT);
    unsigned short* ABF = (unsigned short*)(wsb + B_ABF);
    unsigned short* WQT = (unsigned short*)(wsb + B_WQT);
    unsigned short* RBF = (unsigned short*)(wsb + B_RBF);
    unsigned short* WRT = (unsigned short*)(wsb + B_WRT);
    unsigned short* WOT = (unsigned short*)(wsb + B_WOT);

    // converts
    cvt_cat<<<4096, 256, 0, stream>>>(mems, w, ABF);
    cvt_r<<<512, 256, 0, stream>>>(r, RBF);
    tcvt<<<dim3(48, 16), 256, 0, stream>>>(Wqkv, WQT, 512, 1536);
    tcvt<<<dim3(16, 16), 256, 0, stream>>>(Wr, WRT, 512, 512);
    tcvt<<<dim3(16, 16), 256, 0, stream>>>(Wo, WOT, 512, 512);
    zpad_r<<<32, 256, 0, stream>>>(Rg);

    // projections (MFMA)
    gemm_mfma<0><<<dim3(12, 128), 256, 0, stream>>>(ABF, WQT, rwb, rrb, QW, QR, Kg, VT, nullptr, nullptr);
    gemm_mfma<1><<<dim3(4, 16), 256, 0, stream>>>(RBF, WRT, nullptr, nullptr,
                                                  nullptr, nullptr, nullptr, nullptr, Rg, nullptr);

    // attention + entropy
    attn_mfma<<<dim3(16, 64), 256, 0, stream>>>(QW, QR, Kg, VT, Rg, AVB, ENT);
    reduce_ent<<<1, 64, 0, stream>>>(ENT, out);

    // output projection (MFMA)
    gemm_mfma<2><<<dim3(4, 64), 256, 0, stream>>>(AVB, WOT, nullptr, nullptr,
                                                  nullptr, nullptr, nullptr, nullptr, nullptr, out);
}

// Round 8
// 292.102 us; speedup vs baseline: 15.1088x; 1.1689x over previous
//
#include <hip/hip_runtime.h>
#include <hip/hip_bf16.h>

// Transformer-XL RelPartialLearnableMultiHeadAttn — round 8: attn prefetch pipeline.
// Register double-buffered K/V/R staging (issue-early/write-late, raw s_barrier to
// keep prefetch loads in flight across the barrier) + BD computed as one 16x80
// strip per wave (10 MFMA vs 16). GEMMs/converts unchanged from round 7.

#define QLEN 1024
#define MLEN 1024
#define KLEN 2048
#define BSZ 8
#define DMODEL 512
#define NHEAD 8
#define DHEAD 64
#define SCALE 0.125f
#define RPAD 2176

// workspace byte offsets
#define B_QW   0u            // bf16 [bn][1024][64]
#define B_QR   8388608u      // bf16 [bn][1024][64]
#define B_K    16777216u     // bf16 [bn][2048][64]
#define B_VT   33554432u     // bf16 [bn][64][2048]
#define B_R    50331648u     // bf16 [n][2176][64]
#define B_AVB  52559872u     // bf16 [i*8+b][512]
#define B_ENT  60948480u     // f32  [bn][16]
#define B_ABF  60952576u     // bf16 [16384][512] cat(mems,w)
#define B_WQT  77729792u     // bf16 [1536][512]  W_qkv^T
#define B_RBF  79302656u     // bf16 [2048][512]  r
#define B_WRT  81399808u     // bf16 [512][512]   W_r^T
#define B_WOT  81924096u     // bf16 [512][512]   W_o^T

typedef short bf16x8 __attribute__((ext_vector_type(8)));
typedef float f32x4  __attribute__((ext_vector_type(4)));

// XOR-swizzle within a [row][64]bf16 (128B-row) tile: 16B-chunk ^= row&7
#define SWZ(row, byte) ((((row) << 7) + (((((byte) >> 4) ^ ((row) & 7)) << 4)) + ((byte) & 15)))

__device__ __forceinline__ unsigned short f2bf(float f) {
    union { float f; unsigned int u; } v; v.f = f;
    unsigned int r = v.u + 0x7FFFu + ((v.u >> 16) & 1u);
    return (unsigned short)(r >> 16);
}

// ---- cast cat(mems,w) -> bf16 [16384][512] --------------------------------
__global__ __launch_bounds__(256) void cvt_cat(const float* __restrict__ mems,
                                               const float* __restrict__ w,
                                               unsigned short* __restrict__ Abf) {
    size_t e = ((size_t)blockIdx.x * 256 + threadIdx.x) * 8;
    int m = (int)(e >> 9), k = (int)(e & 511);
    int t = m >> 3, b = m & 7;
    const float* src = (t < MLEN) ? mems + ((size_t)t * 8 + b) * 512 + k
                                  : w    + ((size_t)(t - MLEN) * 8 + b) * 512 + k;
    float4 v0 = *reinterpret_cast<const float4*>(src);
    float4 v1 = *reinterpret_cast<const float4*>(src + 4);
    ushort4 o0, o1;
    o0.x = f2bf(v0.x); o0.y = f2bf(v0.y); o0.z = f2bf(v0.z); o0.w = f2bf(v0.w);
    o1.x = f2bf(v1.x); o1.y = f2bf(v1.y); o1.z = f2bf(v1.z); o1.w = f2bf(v1.w);
    *reinterpret_cast<ushort4*>(Abf + e)     = o0;
    *reinterpret_cast<ushort4*>(Abf + e + 4) = o1;
}

// ---- cast r -> bf16 [2048][512] -------------------------------------------
__global__ __launch_bounds__(256) void cvt_r(const float* __restrict__ r,
                                             unsigned short* __restrict__ rbf) {
    size_t e = ((size_t)blockIdx.x * 256 + threadIdx.x) * 8;
    float4 v0 = *reinterpret_cast<const float4*>(r + e);
    float4 v1 = *reinterpret_cast<const float4*>(r + e + 4);
    ushort4 o0, o1;
    o0.x = f2bf(v0.x); o0.y = f2bf(v0.y); o0.z = f2bf(v0.z); o0.w = f2bf(v0.w);
    o1.x = f2bf(v1.x); o1.y = f2bf(v1.y); o1.z = f2bf(v1.z); o1.w = f2bf(v1.w);
    *reinterpret_cast<ushort4*>(rbf + e)     = o0;
    *reinterpret_cast<ushort4*>(rbf + e + 4) = o1;
}

// ---- transpose+cast: S[R][C] f32 -> D[C][R] bf16 --------------------------
__global__ __launch_bounds__(256) void tcvt(const float* __restrict__ S,
                                            unsigned short* __restrict__ D,
                                            int R, int C) {
    __shared__ float t[32][33];
    int bx = blockIdx.x * 32;
    int by = blockIdx.y * 32;
    int x = threadIdx.x & 31, y = threadIdx.x >> 5;
    #pragma unroll
    for (int q = 0; q < 4; ++q)
        t[y + q * 8][x] = S[(size_t)(by + y + q * 8) * C + bx + x];
    __syncthreads();
    #pragma unroll
    for (int q = 0; q < 4; ++q)
        D[(size_t)(bx + y + q * 8) * R + by + x] = f2bf(t[x][y + q * 8]);
}

// ---- zero pad rows 2048..2175 of Rg ---------------------------------------
__global__ void zpad_r(unsigned short* __restrict__ Rg) {
    int idx = blockIdx.x * 256 + threadIdx.x;
    int n = idx >> 10, o = idx & 1023;
    uint4 z = make_uint4(0, 0, 0, 0);
    *reinterpret_cast<uint4*>(Rg + ((size_t)n * RPAD + KLEN) * 64 + o * 8) = z;
}

// ---------------------------------------------------------------------------
// bf16 MFMA GEMM: C[M][N] = A[M][512] @ Bt[N][512]^T. 128x128 tile, 4 waves.
// ---------------------------------------------------------------------------
template<int MODE>
__global__ __launch_bounds__(256) void gemm_mfma(const unsigned short* __restrict__ A,
                                                 const unsigned short* __restrict__ Bt,
                                                 const float* __restrict__ rwb,
                                                 const float* __restrict__ rrb,
                                                 unsigned short* __restrict__ QW,
                                                 unsigned short* __restrict__ QR,
                                                 unsigned short* __restrict__ Kg,
                                                 unsigned short* __restrict__ VT,
                                                 unsigned short* __restrict__ Rg,
                                                 float* __restrict__ Cout) {
    __shared__ unsigned short Als[128][72];
    __shared__ unsigned short Bls[128][72];
    const int tid = threadIdx.x;
    const int wv = tid >> 6, lane = tid & 63, lg = lane >> 4, lc = lane & 15;
    const int wr = wv >> 1, wc = wv & 1;
    const int n0 = blockIdx.x * 128;
    const int m0 = blockIdx.y * 128;

    f32x4 acc[4][4];
    #pragma unroll
    for (int mi = 0; mi < 4; ++mi)
        #pragma unroll
        for (int ni = 0; ni < 4; ++ni)
            acc[mi][ni] = (f32x4){0.f, 0.f, 0.f, 0.f};

    for (int k0 = 0; k0 < 512; k0 += 64) {
        __syncthreads();
        #pragma unroll
        for (int q = 0; q < 4; ++q) {
            int c = q * 256 + tid;
            int row = c >> 3, off = (c & 7) * 8;
            *reinterpret_cast<uint4*>(&Als[row][off]) =
                *reinterpret_cast<const uint4*>(A + (size_t)(m0 + row) * 512 + k0 + off);
            *reinterpret_cast<uint4*>(&Bls[row][off]) =
                *reinterpret_cast<const uint4*>(Bt + (size_t)(n0 + row) * 512 + k0 + off);
        }
        __syncthreads();
        #pragma unroll
        for (int kk = 0; kk < 2; ++kk) {
            bf16x8 af[4], bfr[4];
            #pragma unroll
            for (int mi = 0; mi < 4; ++mi)
                af[mi] = *reinterpret_cast<const bf16x8*>(&Als[64 * wr + 16 * mi + lc][32 * kk + lg * 8]);
            #pragma unroll
            for (int ni = 0; ni < 4; ++ni)
                bfr[ni] = *reinterpret_cast<const bf16x8*>(&Bls[64 * wc + 16 * ni + lc][32 * kk + lg * 8]);
            #pragma unroll
            for (int mi = 0; mi < 4; ++mi)
                #pragma unroll
                for (int ni = 0; ni < 4; ++ni)
                    acc[mi][ni] = __builtin_amdgcn_mfma_f32_16x16x32_bf16(af[mi], bfr[ni], acc[mi][ni], 0, 0, 0);
        }
    }

    #pragma unroll
    for (int mi = 0; mi < 4; ++mi) {
        #pragma unroll
        for (int ni = 0; ni < 4; ++ni) {
            const int n = n0 + 64 * wc + 16 * ni + lc;
            float bw = 0.f, br = 0.f;
            int region = 0, hn = 0, d = 0;
            if (MODE == 0) {
                region = n >> 9; int cr = n & 511; hn = cr >> 6; d = cr & 63;
                if (region == 0) { bw = rwb[hn * 64 + d]; br = rrb[hn * 64 + d]; }
            }
            #pragma unroll
            for (int reg = 0; reg < 4; ++reg) {
                const int m = m0 + 64 * wr + 16 * mi + lg * 4 + reg;
                const float val = acc[mi][ni][reg];
                if (MODE == 0) {
                    int t = m >> 3, b = m & 7, bn = b * 8 + hn;
                    if (region == 0) {
                        if (t >= MLEN) {
                            size_t base = ((size_t)bn * QLEN + (t - MLEN)) * 64 + d;
                            QW[base] = f2bf(val + bw);
                            QR[base] = f2bf(val + br);
                        }
                    } else if (region == 1) {
                        Kg[((size_t)bn * KLEN + t) * 64 + d] = f2bf(val);
                    } else {
                        VT[((size_t)bn * 64 + d) * KLEN + t] = f2bf(val);
                    }
                } else if (MODE == 1) {
                    Rg[((size_t)(n >> 6) * RPAD + m) * 64 + (n & 63)] = f2bf(val);
                } else {
                    Cout[(size_t)m * 512 + n] = val;
                }
            }
        }
    }
}

// ---------------------------------------------------------------------------
// MFMA attention, swizzled LDS + reg-prefetch pipeline + BD strip.
// grid (16 i-tiles, 64 bn), 4 waves.
// ---------------------------------------------------------------------------
__global__ __launch_bounds__(256, 3) void attn_mfma(const unsigned short* __restrict__ QWg,
                                                    const unsigned short* __restrict__ QRg,
                                                    const unsigned short* __restrict__ Kg,
                                                    const unsigned short* __restrict__ VTg,
                                                    const unsigned short* __restrict__ Rg,
                                                    unsigned short* __restrict__ AVB,
                                                    float* __restrict__ ENT) {
    __shared__ __attribute__((aligned(16))) unsigned short Klds[64 * 64];    //  8 KB
    __shared__ __attribute__((aligned(16))) unsigned short Rblds[128 * 64];  // 16 KB
    __shared__ __attribute__((aligned(16))) unsigned short Vtlds[64 * 64];   //  8 KB
    __shared__ __attribute__((aligned(16))) unsigned short Plds[64 * 64];    //  8 KB

    const int tid = threadIdx.x;
    const int w = tid >> 6, lane = tid & 63, lg = lane >> 4, lc = lane & 15;
    const int i0 = blockIdx.x * 64;
    const int bn = blockIdx.y, b = bn >> 3, n = bn & 7;
    const int srow = tid >> 3;      // staging row 0..31
    const int sch  = tid & 7;       // staging 16B-chunk 0..7

    // ---- stage QW/QR i-tiles and pull persistent A-frags ----
    {
        const unsigned short* qwsrc = QWg + ((size_t)bn * QLEN + i0) * 64;
        const unsigned short* qrsrc = QRg + ((size_t)bn * QLEN + i0) * 64;
        #pragma unroll
        for (int q = 0; q < 2; ++q) {
            int row = srow + q * 32;
            *reinterpret_cast<uint4*>((char*)Klds + SWZ(row, sch * 16)) =
                *reinterpret_cast<const uint4*>(qwsrc + (size_t)row * 64 + sch * 8);
            *reinterpret_cast<uint4*>((char*)Rblds + SWZ(row, sch * 16)) =
                *reinterpret_cast<const uint4*>(qrsrc + (size_t)row * 64 + sch * 8);
        }
    }
    __syncthreads();
    bf16x8 aqw[2], aqr[2];
    #pragma unroll
    for (int k = 0; k < 2; ++k) {
        aqw[k] = *reinterpret_cast<const bf16x8*>((const char*)Klds + SWZ(16 * w + lc, 64 * k + 16 * lg));
        aqr[k] = *reinterpret_cast<const bf16x8*>((const char*)Rblds + SWZ(16 * w + lc, 64 * k + 16 * lg));
    }

    f32x4 Ofr[4];
    #pragma unroll
    for (int t = 0; t < 4; ++t) Ofr[t] = (f32x4){0.f, 0.f, 0.f, 0.f};
    float mreg[4] = {-1e30f, -1e30f, -1e30f, -1e30f};
    float lpart[4] = {0.f, 0.f, 0.f, 0.f};
    float tpart[4] = {0.f, 0.f, 0.f, 0.f};

    const int nj = (i0 >> 6) + 17;
    const unsigned short* kbase = Kg  + (size_t)bn * KLEN * 64;
    const unsigned short* vbase = VTg + (size_t)bn * 64 * KLEN;
    const unsigned short* rbase = Rg  + (size_t)n * RPAD * 64 + (size_t)(960 - i0) * 64;

    // ---- prologue: prefetch tile 0 into registers ----
    uint4 kr0, kr1, vr0, vr1, rr0, rr1, rr2, rr3;
    kr0 = *reinterpret_cast<const uint4*>(kbase + (size_t)(srow)      * 64 + sch * 8);
    kr1 = *reinterpret_cast<const uint4*>(kbase + (size_t)(srow + 32) * 64 + sch * 8);
    vr0 = *reinterpret_cast<const uint4*>(vbase + (size_t)(srow)      * KLEN + sch * 8);
    vr1 = *reinterpret_cast<const uint4*>(vbase + (size_t)(srow + 32) * KLEN + sch * 8);
    rr0 = *reinterpret_cast<const uint4*>(rbase + (size_t)(srow)      * 64 + sch * 8);
    rr1 = *reinterpret_cast<const uint4*>(rbase + (size_t)(srow + 32) * 64 + sch * 8);
    rr2 = *reinterpret_cast<const uint4*>(rbase + (size_t)(srow + 64) * 64 + sch * 8);
    rr3 = *reinterpret_cast<const uint4*>(rbase + (size_t)(srow + 96) * 64 + sch * 8);

    for (int jt = 0; jt < nj; ++jt) {
        const int j0 = jt * 64;
        __syncthreads();   // all waves done reading prev tile's LDS (vmcnt drain here is ~free)

        // ---- write staged regs to LDS (swizzled) ----
        *reinterpret_cast<uint4*>((char*)Klds  + SWZ(srow,      sch * 16)) = kr0;
        *reinterpret_cast<uint4*>((char*)Klds  + SWZ(srow + 32, sch * 16)) = kr1;
        *reinterpret_cast<uint4*>((char*)Vtlds + SWZ(srow,      sch * 16)) = vr0;
        *reinterpret_cast<uint4*>((char*)Vtlds + SWZ(srow + 32, sch * 16)) = vr1;
        *reinterpret_cast<uint4*>((char*)Rblds + SWZ(srow,      sch * 16)) = rr0;
        *reinterpret_cast<uint4*>((char*)Rblds + SWZ(srow + 32, sch * 16)) = rr1;
        *reinterpret_cast<uint4*>((char*)Rblds + SWZ(srow + 64, sch * 16)) = rr2;
        *reinterpret_cast<uint4*>((char*)Rblds + SWZ(srow + 96, sch * 16)) = rr3;

        // ---- prefetch next tile (stays in flight across the raw barrier) ----
        if (jt + 1 < nj) {
            const int j1 = j0 + 64;
            kr0 = *reinterpret_cast<const uint4*>(kbase + (size_t)(j1 + srow)      * 64 + sch * 8);
            kr1 = *reinterpret_cast<const uint4*>(kbase + (size_t)(j1 + srow + 32) * 64 + sch * 8);
            vr0 = *reinterpret_cast<const uint4*>(vbase + (size_t)(srow)      * KLEN + j1 + sch * 8);
            vr1 = *reinterpret_cast<const uint4*>(vbase + (size_t)(srow + 32) * KLEN + j1 + sch * 8);
            rr0 = *reinterpret_cast<const uint4*>(rbase + (size_t)(j1 + srow)      * 64 + sch * 8);
            rr1 = *reinterpret_cast<const uint4*>(rbase + (size_t)(j1 + srow + 32) * 64 + sch * 8);
            rr2 = *reinterpret_cast<const uint4*>(rbase + (size_t)(j1 + srow + 64) * 64 + sch * 8);
            rr3 = *reinterpret_cast<const uint4*>(rbase + (size_t)(j1 + srow + 96) * 64 + sch * 8);
        }

        asm volatile("s_waitcnt lgkmcnt(0)" ::: "memory");
        __builtin_amdgcn_sched_barrier(0);
        __builtin_amdgcn_s_barrier();
        asm volatile("" ::: "memory");
        __builtin_amdgcn_sched_barrier(0);

        // ---- BD strip: G[r][c] for c in [0,80), strip row = (48-16w)+c ----
        f32x4 g[5];
        const int sb = 48 - 16 * w;
        #pragma unroll
        for (int cb = 0; cb < 5; ++cb) {
            g[cb] = (f32x4){0.f, 0.f, 0.f, 0.f};
            #pragma unroll
            for (int k = 0; k < 2; ++k) {
                bf16x8 br = *reinterpret_cast<const bf16x8*>((const char*)Rblds + SWZ(sb + 16 * cb + lc, 64 * k + 16 * lg));
                g[cb] = __builtin_amdgcn_mfma_f32_16x16x32_bf16(aqr[k], br, g[cb], 0, 0, 0);
            }
        }

        // ---- scores: AC (MFMA) + strip diag gather ----
        f32x4 sfr[4];
        #pragma unroll
        for (int bj = 0; bj < 4; ++bj) {
            f32x4 acc = (f32x4){0.f, 0.f, 0.f, 0.f};
            #pragma unroll
            for (int k = 0; k < 2; ++k) {
                bf16x8 bk = *reinterpret_cast<const bf16x8*>((const char*)Klds + SWZ(16 * bj + lc, 64 * k + 16 * lg));
                acc = __builtin_amdgcn_mfma_f32_16x16x32_bf16(aqw[k], bk, acc, 0, 0, 0);
            }
            #pragma unroll
            for (int reg = 0; reg < 4; ++reg) {
                int r = lg * 4 + reg;
                int srcl = (lane & 48) | ((lc - r + 15) & 15);
                float s0 = __shfl(g[bj][reg], srcl, 64);
                float s1 = __shfl(g[bj + 1][reg], srcl, 64);
                float gv = (lc <= r) ? s0 : s1;
                sfr[bj][reg] = (acc[reg] + gv) * SCALE;
            }
        }
        if (jt == nj - 1) {   // only the last j-tile can be masked
            #pragma unroll
            for (int bj = 0; bj < 4; ++bj)
                #pragma unroll
                for (int reg = 0; reg < 4; ++reg) {
                    int ii = 16 * w + lg * 4 + reg;
                    int jj = 16 * bj + lc;
                    if (j0 + jj > i0 + ii + MLEN) sfr[bj][reg] = -1e30f;
                }
        }

        // ---- online softmax: shared max, per-lane l/t partials ----
        #pragma unroll
        for (int reg = 0; reg < 4; ++reg) {
            float gmax = fmaxf(fmaxf(sfr[0][reg], sfr[1][reg]), fmaxf(sfr[2][reg], sfr[3][reg]));
            gmax = fmaxf(gmax, __shfl_xor(gmax, 1));
            gmax = fmaxf(gmax, __shfl_xor(gmax, 2));
            gmax = fmaxf(gmax, __shfl_xor(gmax, 4));
            gmax = fmaxf(gmax, __shfl_xor(gmax, 8));
            float mo = mreg[reg], mn = fmaxf(mo, gmax);
            float fac = __expf(mo - mn);
            float le = 0.f, te = 0.f;
            int r = lg * 4 + reg;
            #pragma unroll
            for (int bj = 0; bj < 4; ++bj) {
                float e = __expf(sfr[bj][reg] - mn);
                le += e; te += e * sfr[bj][reg];
                *reinterpret_cast<unsigned short*>((char*)Plds + SWZ(16 * w + r, 2 * (16 * bj + lc))) = f2bf(e);
            }
            lpart[reg] = lpart[reg] * fac + le;
            tpart[reg] = tpart[reg] * fac + te;
            mreg[reg] = mn;
            Ofr[0][reg] *= fac; Ofr[1][reg] *= fac;
            Ofr[2][reg] *= fac; Ofr[3][reg] *= fac;
        }
        asm volatile("s_waitcnt lgkmcnt(0)" ::: "memory");
        __builtin_amdgcn_sched_barrier(0);

        // ---- PV (wave reads only its own P rows) ----
        #pragma unroll
        for (int k = 0; k < 2; ++k) {
            bf16x8 ap = *reinterpret_cast<const bf16x8*>((const char*)Plds + SWZ(16 * w + lc, 64 * k + 16 * lg));
            Ofr[0] = __builtin_amdgcn_mfma_f32_16x16x32_bf16(ap,
                *reinterpret_cast<const bf16x8*>((const char*)Vtlds + SWZ( 0 + lc, 64 * k + 16 * lg)), Ofr[0], 0, 0, 0);
            Ofr[1] = __builtin_amdgcn_mfma_f32_16x16x32_bf16(ap,
                *reinterpret_cast<const bf16x8*>((const char*)Vtlds + SWZ(16 + lc, 64 * k + 16 * lg)), Ofr[1], 0, 0, 0);
            Ofr[2] = __builtin_amdgcn_mfma_f32_16x16x32_bf16(ap,
                *reinterpret_cast<const bf16x8*>((const char*)Vtlds + SWZ(32 + lc, 64 * k + 16 * lg)), Ofr[2], 0, 0, 0);
            Ofr[3] = __builtin_amdgcn_mfma_f32_16x16x32_bf16(ap,
                *reinterpret_cast<const bf16x8*>((const char*)Vtlds + SWZ(48 + lc, 64 * k + 16 * lg)), Ofr[3], 0, 0, 0);
        }
    }

    // ---- final l/t reduction across the 16 lc lanes ----
    float lred[4], tred[4];
    #pragma unroll
    for (int reg = 0; reg < 4; ++reg) {
        float l = lpart[reg], t = tpart[reg];
        l += __shfl_xor(l, 1); l += __shfl_xor(l, 2); l += __shfl_xor(l, 4); l += __shfl_xor(l, 8);
        t += __shfl_xor(t, 1); t += __shfl_xor(t, 2); t += __shfl_xor(t, 4); t += __shfl_xor(t, 8);
        lred[reg] = l; tred[reg] = t;
    }

    // ---- normalize + write attn_vec (bf16) ----
    #pragma unroll
    for (int reg = 0; reg < 4; ++reg) {
        int i = i0 + 16 * w + lg * 4 + reg;
        float inv = 1.f / lred[reg];
        unsigned short* dst = AVB + ((size_t)i * BSZ + b) * DMODEL + n * 64 + lc;
        dst[ 0] = f2bf(Ofr[0][reg] * inv);
        dst[16] = f2bf(Ofr[1][reg] * inv);
        dst[32] = f2bf(Ofr[2][reg] * inv);
        dst[48] = f2bf(Ofr[3][reg] * inv);
    }

    // ---- entropy partial ----
    float h = 0.f;
    if (lc == 0) {
        #pragma unroll
        for (int reg = 0; reg < 4; ++reg)
            h += mreg[reg] + __logf(lred[reg]) - tred[reg] / lred[reg];
    }
    h += __shfl_xor(h, 1);  h += __shfl_xor(h, 2);  h += __shfl_xor(h, 4);
    h += __shfl_xor(h, 8);  h += __shfl_xor(h, 16); h += __shfl_xor(h, 32);
    __syncthreads();
    float* hred = reinterpret_cast<float*>(Klds);
    if (lane == 0) hred[w] = h;
    __syncthreads();
    if (tid == 0) ENT[bn * 16 + (i0 >> 6)] = hred[0] + hred[1] + hred[2] + hred[3];
}

__global__ void reduce_ent(const float* __restrict__ ent, float* __restrict__ out) {
    int n = threadIdx.x;
    if (n < NHEAD) {
        float s = 0.f;
        for (int b = 0; b < BSZ; ++b)
            for (int it = 0; it < 16; ++it)
                s += ent[(b * NHEAD + n) * 16 + it];
        out[(size_t)QLEN * BSZ * DMODEL + n] = s / (float)(QLEN * BSZ);
    }
}

extern "C" void kernel_launch(void* const* d_in, const int* in_sizes, int n_in,
                              void* d_out, int out_size, void* d_ws, size_t ws_size,
                              hipStream_t stream) {
    const float* w    = (const float*)d_in[0];
    const float* r    = (const float*)d_in[1];
    const float* rwb  = (const float*)d_in[2];
    const float* rrb  = (const float*)d_in[3];
    const float* mems = (const float*)d_in[4];
    const float* Wqkv = (const float*)d_in[6];
    const float* Wr   = (const float*)d_in[7];
    const float* Wo   = (const float*)d_in[8];
    float* out = (float*)d_out;
    char*  wsb = (char*)d_ws;

    unsigned short* QW  = (unsigned short*)(wsb + B_QW);
    unsigned short* QR  = (unsigned short*)(wsb + B_QR);
    unsigned short* Kg  = (unsigned short*)(wsb + B_K);
    unsigned short* VT  = (unsigned short*)(wsb + B_VT);
    unsigned short* Rg  = (unsigned short*)(wsb + B_R);
    unsigned short* AVB = (unsigned short*)(wsb + B_AVB);
    float* ENT = (float*)(wsb + B_ENT);
    unsigned short* ABF = (unsigned short*)(wsb + B_ABF);
    unsigned short* WQT = (unsigned short*)(wsb + B_WQT);
    unsigned short* RBF = (unsigned short*)(wsb + B_RBF);
    unsigned short* WRT = (unsigned short*)(wsb + B_WRT);
    unsigned short* WOT = (unsigned short*)(wsb + B_WOT);

    // converts
    cvt_cat<<<4096, 256, 0, stream>>>(mems, w, ABF);
    cvt_r<<<512, 256, 0, stream>>>(r, RBF);
    tcvt<<<dim3(48, 16), 256, 0, stream>>>(Wqkv, WQT, 512, 1536);
    tcvt<<<dim3(16, 16), 256, 0, stream>>>(Wr, WRT, 512, 512);
    tcvt<<<dim3(16, 16), 256, 0, stream>>>(Wo, WOT, 512, 512);
    zpad_r<<<32, 256, 0, stream>>>(Rg);

    // projections (MFMA)
    gemm_mfma<0><<<dim3(12, 128), 256, 0, stream>>>(ABF, WQT, rwb, rrb, QW, QR, Kg, VT, nullptr, nullptr);
    gemm_mfma<1><<<dim3(4, 16), 256, 0, stream>>>(RBF, WRT, nullptr, nullptr,
                                                  nullptr, nullptr, nullptr, nullptr, Rg, nullptr);

    // attention + entropy
    attn_mfma<<<dim3(16, 64), 256, 0, stream>>>(QW, QR, Kg, VT, Rg, AVB, ENT);
    reduce_ent<<<1, 64, 0, stream>>>(ENT, out);

    // output projection (MFMA)
    gemm_mfma<2><<<dim3(4, 64), 256, 0, stream>>>(AVB, WOT, nullptr, nullptr,
                                                  nullptr, nullptr, nullptr, nullptr, nullptr, out);
}

// Round 9
// 257.415 us; speedup vs baseline: 17.1447x; 1.1347x over previous
//
#include <hip/hip_runtime.h>
#include <hip/hip_bf16.h>

// Transformer-XL RelPartialLearnableMultiHeadAttn — round 9: attn balance + DS-op diet.
// (1) iblk remap for per-CU load balance (nj varies 17..32 with iblk; co-resident
//     blocks share x under +256-stride dispatch -> pair x with 15-x via bit4 of y).
// (2) defer-max online softmax (skip max-reduce/rescale unless growth > 8).
// (3) rel-shift gather: shuffle each strip block once (20 bpermutes vs 32).
// (4) s_setprio around MFMA clusters. GEMMs/converts unchanged from round 8.

#define QLEN 1024
#define MLEN 1024
#define KLEN 2048
#define BSZ 8
#define DMODEL 512
#define NHEAD 8
#define DHEAD 64
#define SCALE 0.125f
#define RPAD 2176
#define RTHR 8.0f

// workspace byte offsets
#define B_QW   0u            // bf16 [bn][1024][64]
#define B_QR   8388608u      // bf16 [bn][1024][64]
#define B_K    16777216u     // bf16 [bn][2048][64]
#define B_VT   33554432u     // bf16 [bn][64][2048]
#define B_R    50331648u     // bf16 [n][2176][64]
#define B_AVB  52559872u     // bf16 [i*8+b][512]
#define B_ENT  60948480u     // f32  [bn][16]
#define B_ABF  60952576u     // bf16 [16384][512] cat(mems,w)
#define B_WQT  77729792u     // bf16 [1536][512]  W_qkv^T
#define B_RBF  79302656u     // bf16 [2048][512]  r
#define B_WRT  81399808u     // bf16 [512][512]   W_r^T
#define B_WOT  81924096u     // bf16 [512][512]   W_o^T

typedef short bf16x8 __attribute__((ext_vector_type(8)));
typedef float f32x4  __attribute__((ext_vector_type(4)));

// XOR-swizzle within a [row][64]bf16 (128B-row) tile: 16B-chunk ^= row&7
#define SWZ(row, byte) ((((row) << 7) + (((((byte) >> 4) ^ ((row) & 7)) << 4)) + ((byte) & 15)))

__device__ __forceinline__ unsigned short f2bf(float f) {
    union { float f; unsigned int u; } v; v.f = f;
    unsigned int r = v.u + 0x7FFFu + ((v.u >> 16) & 1u);
    return (unsigned short)(r >> 16);
}

// ---- cast cat(mems,w) -> bf16 [16384][512] --------------------------------
__global__ __launch_bounds__(256) void cvt_cat(const float* __restrict__ mems,
                                               const float* __restrict__ w,
                                               unsigned short* __restrict__ Abf) {
    size_t e = ((size_t)blockIdx.x * 256 + threadIdx.x) * 8;
    int m = (int)(e >> 9), k = (int)(e & 511);
    int t = m >> 3, b = m & 7;
    const float* src = (t < MLEN) ? mems + ((size_t)t * 8 + b) * 512 + k
                                  : w    + ((size_t)(t - MLEN) * 8 + b) * 512 + k;
    float4 v0 = *reinterpret_cast<const float4*>(src);
    float4 v1 = *reinterpret_cast<const float4*>(src + 4);
    ushort4 o0, o1;
    o0.x = f2bf(v0.x); o0.y = f2bf(v0.y); o0.z = f2bf(v0.z); o0.w = f2bf(v0.w);
    o1.x = f2bf(v1.x); o1.y = f2bf(v1.y); o1.z = f2bf(v1.z); o1.w = f2bf(v1.w);
    *reinterpret_cast<ushort4*>(Abf + e)     = o0;
    *reinterpret_cast<ushort4*>(Abf + e + 4) = o1;
}

// ---- cast r -> bf16 [2048][512] -------------------------------------------
__global__ __launch_bounds__(256) void cvt_r(const float* __restrict__ r,
                                             unsigned short* __restrict__ rbf) {
    size_t e = ((size_t)blockIdx.x * 256 + threadIdx.x) * 8;
    float4 v0 = *reinterpret_cast<const float4*>(r + e);
    float4 v1 = *reinterpret_cast<const float4*>(r + e + 4);
    ushort4 o0, o1;
    o0.x = f2bf(v0.x); o0.y = f2bf(v0.y); o0.z = f2bf(v0.z); o0.w = f2bf(v0.w);
    o1.x = f2bf(v1.x); o1.y = f2bf(v1.y); o1.z = f2bf(v1.z); o1.w = f2bf(v1.w);
    *reinterpret_cast<ushort4*>(rbf + e)     = o0;
    *reinterpret_cast<ushort4*>(rbf + e + 4) = o1;
}

// ---- transpose+cast: S[R][C] f32 -> D[C][R] bf16 --------------------------
__global__ __launch_bounds__(256) void tcvt(const float* __restrict__ S,
                                            unsigned short* __restrict__ D,
                                            int R, int C) {
    __shared__ float t[32][33];
    int bx = blockIdx.x * 32;
    int by = blockIdx.y * 32;
    int x = threadIdx.x & 31, y = threadIdx.x >> 5;
    #pragma unroll
    for (int q = 0; q < 4; ++q)
        t[y + q * 8][x] = S[(size_t)(by + y + q * 8) * C + bx + x];
    __syncthreads();
    #pragma unroll
    for (int q = 0; q < 4; ++q)
        D[(size_t)(bx + y + q * 8) * R + by + x] = f2bf(t[x][y + q * 8]);
}

// ---- zero pad rows 2048..2175 of Rg ---------------------------------------
__global__ void zpad_r(unsigned short* __restrict__ Rg) {
    int idx = blockIdx.x * 256 + threadIdx.x;
    int n = idx >> 10, o = idx & 1023;
    uint4 z = make_uint4(0, 0, 0, 0);
    *reinterpret_cast<uint4*>(Rg + ((size_t)n * RPAD + KLEN) * 64 + o * 8) = z;
}

// ---------------------------------------------------------------------------
// bf16 MFMA GEMM: C[M][N] = A[M][512] @ Bt[N][512]^T. 128x128 tile, 4 waves.
// ---------------------------------------------------------------------------
template<int MODE>
__global__ __launch_bounds__(256) void gemm_mfma(const unsigned short* __restrict__ A,
                                                 const unsigned short* __restrict__ Bt,
                                                 const float* __restrict__ rwb,
                                                 const float* __restrict__ rrb,
                                                 unsigned short* __restrict__ QW,
                                                 unsigned short* __restrict__ QR,
                                                 unsigned short* __restrict__ Kg,
                                                 unsigned short* __restrict__ VT,
                                                 unsigned short* __restrict__ Rg,
                                                 float* __restrict__ Cout) {
    __shared__ unsigned short Als[128][72];
    __shared__ unsigned short Bls[128][72];
    const int tid = threadIdx.x;
    const int wv = tid >> 6, lane = tid & 63, lg = lane >> 4, lc = lane & 15;
    const int wr = wv >> 1, wc = wv & 1;
    const int n0 = blockIdx.x * 128;
    const int m0 = blockIdx.y * 128;

    f32x4 acc[4][4];
    #pragma unroll
    for (int mi = 0; mi < 4; ++mi)
        #pragma unroll
        for (int ni = 0; ni < 4; ++ni)
            acc[mi][ni] = (f32x4){0.f, 0.f, 0.f, 0.f};

    for (int k0 = 0; k0 < 512; k0 += 64) {
        __syncthreads();
        #pragma unroll
        for (int q = 0; q < 4; ++q) {
            int c = q * 256 + tid;
            int row = c >> 3, off = (c & 7) * 8;
            *reinterpret_cast<uint4*>(&Als[row][off]) =
                *reinterpret_cast<const uint4*>(A + (size_t)(m0 + row) * 512 + k0 + off);
            *reinterpret_cast<uint4*>(&Bls[row][off]) =
                *reinterpret_cast<const uint4*>(Bt + (size_t)(n0 + row) * 512 + k0 + off);
        }
        __syncthreads();
        #pragma unroll
        for (int kk = 0; kk < 2; ++kk) {
            bf16x8 af[4], bfr[4];
            #pragma unroll
            for (int mi = 0; mi < 4; ++mi)
                af[mi] = *reinterpret_cast<const bf16x8*>(&Als[64 * wr + 16 * mi + lc][32 * kk + lg * 8]);
            #pragma unroll
            for (int ni = 0; ni < 4; ++ni)
                bfr[ni] = *reinterpret_cast<const bf16x8*>(&Bls[64 * wc + 16 * ni + lc][32 * kk + lg * 8]);
            #pragma unroll
            for (int mi = 0; mi < 4; ++mi)
                #pragma unroll
                for (int ni = 0; ni < 4; ++ni)
                    acc[mi][ni] = __builtin_amdgcn_mfma_f32_16x16x32_bf16(af[mi], bfr[ni], acc[mi][ni], 0, 0, 0);
        }
    }

    #pragma unroll
    for (int mi = 0; mi < 4; ++mi) {
        #pragma unroll
        for (int ni = 0; ni < 4; ++ni) {
            const int n = n0 + 64 * wc + 16 * ni + lc;
            float bw = 0.f, br = 0.f;
            int region = 0, hn = 0, d = 0;
            if (MODE == 0) {
                region = n >> 9; int cr = n & 511; hn = cr >> 6; d = cr & 63;
                if (region == 0) { bw = rwb[hn * 64 + d]; br = rrb[hn * 64 + d]; }
            }
            #pragma unroll
            for (int reg = 0; reg < 4; ++reg) {
                const int m = m0 + 64 * wr + 16 * mi + lg * 4 + reg;
                const float val = acc[mi][ni][reg];
                if (MODE == 0) {
                    int t = m >> 3, b = m & 7, bn = b * 8 + hn;
                    if (region == 0) {
                        if (t >= MLEN) {
                            size_t base = ((size_t)bn * QLEN + (t - MLEN)) * 64 + d;
                            QW[base] = f2bf(val + bw);
                            QR[base] = f2bf(val + br);
                        }
                    } else if (region == 1) {
                        Kg[((size_t)bn * KLEN + t) * 64 + d] = f2bf(val);
                    } else {
                        VT[((size_t)bn * 64 + d) * KLEN + t] = f2bf(val);
                    }
                } else if (MODE == 1) {
                    Rg[((size_t)(n >> 6) * RPAD + m) * 64 + (n & 63)] = f2bf(val);
                } else {
                    Cout[(size_t)m * 512 + n] = val;
                }
            }
        }
    }
}

// ---------------------------------------------------------------------------
// MFMA attention: swizzled LDS + reg-prefetch + BD strip + defer-max softmax.
// grid (16, 64) remapped for load balance: iblk = bit4(y) ? 15-x : x.
// ---------------------------------------------------------------------------
__global__ __launch_bounds__(256, 3) void attn_mfma(const unsigned short* __restrict__ QWg,
                                                    const unsigned short* __restrict__ QRg,
                                                    const unsigned short* __restrict__ Kg,
                                                    const unsigned short* __restrict__ VTg,
                                                    const unsigned short* __restrict__ Rg,
                                                    unsigned short* __restrict__ AVB,
                                                    float* __restrict__ ENT) {
    __shared__ __attribute__((aligned(16))) unsigned short Klds[64 * 64];    //  8 KB
    __shared__ __attribute__((aligned(16))) unsigned short Rblds[128 * 64];  // 16 KB
    __shared__ __attribute__((aligned(16))) unsigned short Vtlds[64 * 64];   //  8 KB
    __shared__ __attribute__((aligned(16))) unsigned short Plds[64 * 64];    //  8 KB

    const int tid = threadIdx.x;
    const int w = tid >> 6, lane = tid & 63, lg = lane >> 4, lc = lane & 15;
    // load-balance remap: co-resident blocks (ids +256 apart) flip bit4 of y,
    // pairing iblk x with 15-x -> equal tile-unit totals per CU.
    const int iblk = ((blockIdx.y >> 4) & 1) ? (15 - blockIdx.x) : blockIdx.x;
    const int i0 = iblk * 64;
    const int bn = blockIdx.y, b = bn >> 3, n = bn & 7;
    const int srow = tid >> 3;      // staging row 0..31
    const int sch  = tid & 7;       // staging 16B-chunk 0..7

    // ---- stage QW/QR i-tiles and pull persistent A-frags ----
    {
        const unsigned short* qwsrc = QWg + ((size_t)bn * QLEN + i0) * 64;
        const unsigned short* qrsrc = QRg + ((size_t)bn * QLEN + i0) * 64;
        #pragma unroll
        for (int q = 0; q < 2; ++q) {
            int row = srow + q * 32;
            *reinterpret_cast<uint4*>((char*)Klds + SWZ(row, sch * 16)) =
                *reinterpret_cast<const uint4*>(qwsrc + (size_t)row * 64 + sch * 8);
            *reinterpret_cast<uint4*>((char*)Rblds + SWZ(row, sch * 16)) =
                *reinterpret_cast<const uint4*>(qrsrc + (size_t)row * 64 + sch * 8);
        }
    }
    __syncthreads();
    bf16x8 aqw[2], aqr[2];
    #pragma unroll
    for (int k = 0; k < 2; ++k) {
        aqw[k] = *reinterpret_cast<const bf16x8*>((const char*)Klds + SWZ(16 * w + lc, 64 * k + 16 * lg));
        aqr[k] = *reinterpret_cast<const bf16x8*>((const char*)Rblds + SWZ(16 * w + lc, 64 * k + 16 * lg));
    }

    f32x4 Ofr[4];
    #pragma unroll
    for (int t = 0; t < 4; ++t) Ofr[t] = (f32x4){0.f, 0.f, 0.f, 0.f};
    float mreg[4] = {-1e30f, -1e30f, -1e30f, -1e30f};
    float lpart[4] = {0.f, 0.f, 0.f, 0.f};
    float tpart[4] = {0.f, 0.f, 0.f, 0.f};

    const int nj = iblk + 17;
    const unsigned short* kbase = Kg  + (size_t)bn * KLEN * 64;
    const unsigned short* vbase = VTg + (size_t)bn * 64 * KLEN;
    const unsigned short* rbase = Rg  + (size_t)n * RPAD * 64 + (size_t)(960 - i0) * 64;

    // ---- prologue: prefetch tile 0 into registers ----
    uint4 kr0, kr1, vr0, vr1, rr0, rr1, rr2, rr3;
    kr0 = *reinterpret_cast<const uint4*>(kbase + (size_t)(srow)      * 64 + sch * 8);
    kr1 = *reinterpret_cast<const uint4*>(kbase + (size_t)(srow + 32) * 64 + sch * 8);
    vr0 = *reinterpret_cast<const uint4*>(vbase + (size_t)(srow)      * KLEN + sch * 8);
    vr1 = *reinterpret_cast<const uint4*>(vbase + (size_t)(srow + 32) * KLEN + sch * 8);
    rr0 = *reinterpret_cast<const uint4*>(rbase + (size_t)(srow)      * 64 + sch * 8);
    rr1 = *reinterpret_cast<const uint4*>(rbase + (size_t)(srow + 32) * 64 + sch * 8);
    rr2 = *reinterpret_cast<const uint4*>(rbase + (size_t)(srow + 64) * 64 + sch * 8);
    rr3 = *reinterpret_cast<const uint4*>(rbase + (size_t)(srow + 96) * 64 + sch * 8);

    for (int jt = 0; jt < nj; ++jt) {
        const int j0 = jt * 64;
        __syncthreads();

        // ---- write staged regs to LDS (swizzled) ----
        *reinterpret_cast<uint4*>((char*)Klds  + SWZ(srow,      sch * 16)) = kr0;
        *reinterpret_cast<uint4*>((char*)Klds  + SWZ(srow + 32, sch * 16)) = kr1;
        *reinterpret_cast<uint4*>((char*)Vtlds + SWZ(srow,      sch * 16)) = vr0;
        *reinterpret_cast<uint4*>((char*)Vtlds + SWZ(srow + 32, sch * 16)) = vr1;
        *reinterpret_cast<uint4*>((char*)Rblds + SWZ(srow,      sch * 16)) = rr0;
        *reinterpret_cast<uint4*>((char*)Rblds + SWZ(srow + 32, sch * 16)) = rr1;
        *reinterpret_cast<uint4*>((char*)Rblds + SWZ(srow + 64, sch * 16)) = rr2;
        *reinterpret_cast<uint4*>((char*)Rblds + SWZ(srow + 96, sch * 16)) = rr3;

        // ---- prefetch next tile (stays in flight across the raw barrier) ----
        if (jt + 1 < nj) {
            const int j1 = j0 + 64;
            kr0 = *reinterpret_cast<const uint4*>(kbase + (size_t)(j1 + srow)      * 64 + sch * 8);
            kr1 = *reinterpret_cast<const uint4*>(kbase + (size_t)(j1 + srow + 32) * 64 + sch * 8);
            vr0 = *reinterpret_cast<const uint4*>(vbase + (size_t)(srow)      * KLEN + j1 + sch * 8);
            vr1 = *reinterpret_cast<const uint4*>(vbase + (size_t)(srow + 32) * KLEN + j1 + sch * 8);
            rr0 = *reinterpret_cast<const uint4*>(rbase + (size_t)(j1 + srow)      * 64 + sch * 8);
            rr1 = *reinterpret_cast<const uint4*>(rbase + (size_t)(j1 + srow + 32) * 64 + sch * 8);
            rr2 = *reinterpret_cast<const uint4*>(rbase + (size_t)(j1 + srow + 64) * 64 + sch * 8);
            rr3 = *reinterpret_cast<const uint4*>(rbase + (size_t)(j1 + srow + 96) * 64 + sch * 8);
        }

        asm volatile("s_waitcnt lgkmcnt(0)" ::: "memory");
        __builtin_amdgcn_sched_barrier(0);
        __builtin_amdgcn_s_barrier();
        asm volatile("" ::: "memory");
        __builtin_amdgcn_sched_barrier(0);

        __builtin_amdgcn_s_setprio(1);
        // ---- AC: all 4 col-blocks ----
        f32x4 sfr[4];
        #pragma unroll
        for (int bj = 0; bj < 4; ++bj) {
            f32x4 acc = (f32x4){0.f, 0.f, 0.f, 0.f};
            #pragma unroll
            for (int k = 0; k < 2; ++k) {
                bf16x8 bk = *reinterpret_cast<const bf16x8*>((const char*)Klds + SWZ(16 * bj + lc, 64 * k + 16 * lg));
                acc = __builtin_amdgcn_mfma_f32_16x16x32_bf16(aqw[k], bk, acc, 0, 0, 0);
            }
            sfr[bj] = acc;
        }
        // ---- BD strip: G[r][c] for c in [0,80), strip row = (48-16w)+c ----
        f32x4 g[5];
        const int sb = 48 - 16 * w;
        #pragma unroll
        for (int cb = 0; cb < 5; ++cb) {
            g[cb] = (f32x4){0.f, 0.f, 0.f, 0.f};
            #pragma unroll
            for (int k = 0; k < 2; ++k) {
                bf16x8 br = *reinterpret_cast<const bf16x8*>((const char*)Rblds + SWZ(sb + 16 * cb + lc, 64 * k + 16 * lg));
                g[cb] = __builtin_amdgcn_mfma_f32_16x16x32_bf16(aqr[k], br, g[cb], 0, 0, 0);
            }
        }
        __builtin_amdgcn_s_setprio(0);

        // ---- diag gather (one shuffle per strip block) + combine ----
        #pragma unroll
        for (int reg = 0; reg < 4; ++reg) {
            int r = lg * 4 + reg;
            int srcl = (lane & 48) | ((lc - r + 15) & 15);
            float gg[5];
            #pragma unroll
            for (int cb = 0; cb < 5; ++cb)
                gg[cb] = __shfl(g[cb][reg], srcl, 64);
            #pragma unroll
            for (int bj = 0; bj < 4; ++bj) {
                float gv = (lc <= r) ? gg[bj] : gg[bj + 1];
                sfr[bj][reg] = (sfr[bj][reg] + gv) * SCALE;
            }
        }
        if (jt == nj - 1) {   // only the last j-tile can be masked
            #pragma unroll
            for (int bj = 0; bj < 4; ++bj)
                #pragma unroll
                for (int reg = 0; reg < 4; ++reg) {
                    int ii = 16 * w + lg * 4 + reg;
                    int jj = 16 * bj + lc;
                    if (j0 + jj > i0 + ii + MLEN) sfr[bj][reg] = -1e30f;
                }
        }

        // ---- defer-max online softmax ----
        float pm[4];
        #pragma unroll
        for (int reg = 0; reg < 4; ++reg)
            pm[reg] = fmaxf(fmaxf(sfr[0][reg], sfr[1][reg]), fmaxf(sfr[2][reg], sfr[3][reg]));
        bool grow = (pm[0] > mreg[0] + RTHR) || (pm[1] > mreg[1] + RTHR) ||
                    (pm[2] > mreg[2] + RTHR) || (pm[3] > mreg[3] + RTHR);
        if (__any(grow)) {
            #pragma unroll
            for (int reg = 0; reg < 4; ++reg) {
                float gmax = pm[reg];
                gmax = fmaxf(gmax, __shfl_xor(gmax, 1));
                gmax = fmaxf(gmax, __shfl_xor(gmax, 2));
                gmax = fmaxf(gmax, __shfl_xor(gmax, 4));
                gmax = fmaxf(gmax, __shfl_xor(gmax, 8));
                float mo = mreg[reg], mn = fmaxf(mo, gmax);
                float fac = __expf(mo - mn);
                lpart[reg] *= fac; tpart[reg] *= fac; mreg[reg] = mn;
                Ofr[0][reg] *= fac; Ofr[1][reg] *= fac;
                Ofr[2][reg] *= fac; Ofr[3][reg] *= fac;
            }
        }
        #pragma unroll
        for (int reg = 0; reg < 4; ++reg) {
            float mn = mreg[reg];
            float le = 0.f, te = 0.f;
            int r = lg * 4 + reg;
            #pragma unroll
            for (int bj = 0; bj < 4; ++bj) {
                float e = __expf(sfr[bj][reg] - mn);
                le += e; te += e * sfr[bj][reg];
                *reinterpret_cast<unsigned short*>((char*)Plds + SWZ(16 * w + r, 2 * (16 * bj + lc))) = f2bf(e);
            }
            lpart[reg] += le;
            tpart[reg] += te;
        }
        asm volatile("s_waitcnt lgkmcnt(0)" ::: "memory");
        __builtin_amdgcn_sched_barrier(0);

        // ---- PV (P is wave-private) ----
        __builtin_amdgcn_s_setprio(1);
        #pragma unroll
        for (int k = 0; k < 2; ++k) {
            bf16x8 ap = *reinterpret_cast<const bf16x8*>((const char*)Plds + SWZ(16 * w + lc, 64 * k + 16 * lg));
            Ofr[0] = __builtin_amdgcn_mfma_f32_16x16x32_bf16(ap,
                *reinterpret_cast<const bf16x8*>((const char*)Vtlds + SWZ( 0 + lc, 64 * k + 16 * lg)), Ofr[0], 0, 0, 0);
            Ofr[1] = __builtin_amdgcn_mfma_f32_16x16x32_bf16(ap,
                *reinterpret_cast<const bf16x8*>((const char*)Vtlds + SWZ(16 + lc, 64 * k + 16 * lg)), Ofr[1], 0, 0, 0);
            Ofr[2] = __builtin_amdgcn_mfma_f32_16x16x32_bf16(ap,
                *reinterpret_cast<const bf16x8*>((const char*)Vtlds + SWZ(32 + lc, 64 * k + 16 * lg)), Ofr[2], 0, 0, 0);
            Ofr[3] = __builtin_amdgcn_mfma_f32_16x16x32_bf16(ap,
                *reinterpret_cast<const bf16x8*>((const char*)Vtlds + SWZ(48 + lc, 64 * k + 16 * lg)), Ofr[3], 0, 0, 0);
        }
        __builtin_amdgcn_s_setprio(0);
    }

    // ---- final l/t reduction across the 16 lc lanes ----
    float lred[4], tred[4];
    #pragma unroll
    for (int reg = 0; reg < 4; ++reg) {
        float l = lpart[reg], t = tpart[reg];
        l += __shfl_xor(l, 1); l += __shfl_xor(l, 2); l += __shfl_xor(l, 4); l += __shfl_xor(l, 8);
        t += __shfl_xor(t, 1); t += __shfl_xor(t, 2); t += __shfl_xor(t, 4); t += __shfl_xor(t, 8);
        lred[reg] = l; tred[reg] = t;
    }

    // ---- normalize + write attn_vec (bf16) ----
    #pragma unroll
    for (int reg = 0; reg < 4; ++reg) {
        int i = i0 + 16 * w + lg * 4 + reg;
        float inv = 1.f / lred[reg];
        unsigned short* dst = AVB + ((size_t)i * BSZ + b) * DMODEL + n * 64 + lc;
        dst[ 0] = f2bf(Ofr[0][reg] * inv);
        dst[16] = f2bf(Ofr[1][reg] * inv);
        dst[32] = f2bf(Ofr[2][reg] * inv);
        dst[48] = f2bf(Ofr[3][reg] * inv);
    }

    // ---- entropy partial ----
    float h = 0.f;
    if (lc == 0) {
        #pragma unroll
        for (int reg = 0; reg < 4; ++reg)
            h += mreg[reg] + __logf(lred[reg]) - tred[reg] / lred[reg];
    }
    h += __shfl_xor(h, 1);  h += __shfl_xor(h, 2);  h += __shfl_xor(h, 4);
    h += __shfl_xor(h, 8);  h += __shfl_xor(h, 16); h += __shfl_xor(h, 32);
    __syncthreads();
    float* hred = reinterpret_cast<float*>(Klds);
    if (lane == 0) hred[w] = h;
    __syncthreads();
    if (tid == 0) ENT[bn * 16 + iblk] = hred[0] + hred[1] + hred[2] + hred[3];
}

__global__ void reduce_ent(const float* __restrict__ ent, float* __restrict__ out) {
    int n = threadIdx.x;
    if (n < NHEAD) {
        float s = 0.f;
        for (int b = 0; b < BSZ; ++b)
            for (int it = 0; it < 16; ++it)
                s += ent[(b * NHEAD + n) * 16 + it];
        out[(size_t)QLEN * BSZ * DMODEL + n] = s / (float)(QLEN * BSZ);
    }
}

extern "C" void kernel_launch(void* const* d_in, const int* in_sizes, int n_in,
                              void* d_out, int out_size, void* d_ws, size_t ws_size,
                              hipStream_t stream) {
    const float* w    = (const float*)d_in[0];
    const float* r    = (const float*)d_in[1];
    const float* rwb  = (const float*)d_in[2];
    const float* rrb  = (const float*)d_in[3];
    const float* mems = (const float*)d_in[4];
    const float* Wqkv = (const float*)d_in[6];
    const float* Wr   = (const float*)d_in[7];
    const float* Wo   = (const float*)d_in[8];
    float* out = (float*)d_out;
    char*  wsb = (char*)d_ws;

    unsigned short* QW  = (unsigned short*)(wsb + B_QW);
    unsigned short* QR  = (unsigned short*)(wsb + B_QR);
    unsigned short* Kg  = (unsigned short*)(wsb + B_K);
    unsigned short* VT  = (unsigned short*)(wsb + B_VT);
    unsigned short* Rg  = (unsigned short*)(wsb + B_R);
    unsigned short* AVB = (unsigned short*)(wsb + B_AVB);
    float* ENT = (float*)(wsb + B_ENT);
    unsigned short* ABF = (unsigned short*)(wsb + B_ABF);
    unsigned short* WQT = (unsigned short*)(wsb + B_WQT);
    unsigned short* RBF = (unsigned short*)(wsb + B_RBF);
    unsigned short* WRT = (unsigned short*)(wsb + B_WRT);
    unsigned short* WOT = (unsigned short*)(wsb + B_WOT);

    // converts
    cvt_cat<<<4096, 256, 0, stream>>>(mems, w, ABF);
    cvt_r<<<512, 256, 0, stream>>>(r, RBF);
    tcvt<<<dim3(48, 16), 256, 0, stream>>>(Wqkv, WQT, 512, 1536);
    tcvt<<<dim3(16, 16), 256, 0, stream>>>(Wr, WRT, 512, 512);
    tcvt<<<dim3(16, 16), 256, 0, stream>>>(Wo, WOT, 512, 512);
    zpad_r<<<32, 256, 0, stream>>>(Rg);

    // projections (MFMA)
    gemm_mfma<0><<<dim3(12, 128), 256, 0, stream>>>(ABF, WQT, rwb, rrb, QW, QR, Kg, VT, nullptr, nullptr);
    gemm_mfma<1><<<dim3(4, 16), 256, 0, stream>>>(RBF, WRT, nullptr, nullptr,
                                                  nullptr, nullptr, nullptr, nullptr, Rg, nullptr);

    // attention + entropy
    attn_mfma<<<dim3(16, 64), 256, 0, stream>>>(QW, QR, Kg, VT, Rg, AVB, ENT);
    reduce_ent<<<1, 64, 0, stream>>>(ENT, out);

    // output projection (MFMA)
    gemm_mfma<2><<<dim3(4, 64), 256, 0, stream>>>(AVB, WOT, nullptr, nullptr,
                                                  nullptr, nullptr, nullptr, nullptr, nullptr, out);
}